// Round 7
// baseline (8689.706 us; speedup 1.0000x reference)
//
#include <hip/hip_runtime.h>
#include <hip/hip_bf16.h>
#include <hip/hip_fp16.h>
#include <cstdint>

// ---------------------------------------------------------------------------
// RWKV6 attention: f16-MFMA GEMMs + chunked parallel scan.
//   Round 7: time-chunked scan (4 x 512) -> 4x TLP; 2-deep prefetch (proven);
//   4-deep reverted (round-6: spill + VALUBusy collapse).
//   d_out rotates: [xw_h | inb_h] (f16) -> E (packed scan input) -> final f32.
//   Chunk states C (12.6MB) overlay dead wsm region; A products overlay z.
// ---------------------------------------------------------------------------

typedef _Float16 half8 __attribute__((ext_vector_type(8)));
typedef float f32x4 __attribute__((ext_vector_type(4)));
typedef unsigned short ushort8 __attribute__((ext_vector_type(8)));

__device__ __forceinline__ float hbits2f(unsigned short us) {
    __half h; *reinterpret_cast<unsigned short*>(&h) = us; return __half2float(h);
}
__device__ __forceinline__ unsigned short f2h(float f) {
    __half h = __float2half(f);
    return *reinterpret_cast<unsigned short*>(&h);
}
__device__ __forceinline__ float2 up2(unsigned int u) {
    return make_float2(hbits2f((unsigned short)(u & 0xFFFF)),
                       hbits2f((unsigned short)(u >> 16)));
}

// ---------------- generic f32 -> f16 cast (weights) -------------------------
__global__ void cast16(const float* __restrict__ src, __half* __restrict__ dst, int n4)
{
    const int i = blockIdx.x * blockDim.x + threadIdx.x;
    if (i >= n4) return;
    const float4 f = *(const float4*)(src + (size_t)i * 4);
    ushort4 u;
    u.x = f2h(f.x); u.y = f2h(f.y); u.z = f2h(f.z); u.w = f2h(f.w);
    *(ushort4*)(dst + (size_t)i * 4) = u;
}

// ---------------- token shift (f16 out) -------------------------------------
__global__ void k_xw_h(const float* __restrict__ X, const float* __restrict__ mu,
                       __half* __restrict__ XW, int M, int T)
{
    const size_t i4 = (size_t)blockIdx.x * blockDim.x + threadIdx.x;
    if (i4 >= (size_t)M * 256) return;
    const size_t idx = i4 * 4;
    const int m = (int)(idx >> 10);
    const int d = (int)(idx & 1023);
    const int t = m & (T - 1);
    const float4 xv = *(const float4*)(X + idx);
    const float4 m4 = *(const float4*)(mu + d);
    float4 xp = make_float4(0.f, 0.f, 0.f, 0.f);
    if (t > 0) xp = *(const float4*)(X + idx - 1024);
    ushort4 o;
    o.x = f2h(xv.x + (xp.x - xv.x) * m4.x);
    o.y = f2h(xv.y + (xp.y - xv.y) * m4.y);
    o.z = f2h(xv.z + (xp.z - xv.z) * m4.z);
    o.w = f2h(xv.w + (xp.w - xv.w) * m4.w);
    *(ushort4*)(XW + idx) = o;
}

// ---------------- f16 MFMA GEMM: C[M,N] = A[M,K] @ B[N,K]^T -----------------
// epi: 0 f16 plain, 1 f16 tanh, 2 f16 bias+delta-lerp(X), 3 f16 bias, 4 f32 plain
#define TS 40  // LDS row stride in halfs (padded from 32)

__global__ __launch_bounds__(256) void gemm16(
    const __half* __restrict__ A, int lda,
    const __half* __restrict__ B, int ldb,
    void* __restrict__ Cv, int ldc,
    int M, int N, int K,
    const float* __restrict__ bias, int epi,
    const float* __restrict__ X, int T)
{
    __shared__ __align__(16) _Float16 As[128 * TS];
    __shared__ __align__(16) _Float16 Bs[128 * TS];

    const int tid = threadIdx.x;

    // XCD-aware swizzle: consecutive logical blocks (same A-row panel) on one XCD
    const int nwg = gridDim.x * gridDim.y;
    int p = blockIdx.y * gridDim.x + blockIdx.x;
    if (!(nwg & 7)) p = (p & 7) * (nwg >> 3) + (p >> 3);
    const int bx = p % gridDim.x, by = p / gridDim.x;

    const int m0 = by * 128;
    const int n0 = bx * 128;
    const int wave = tid >> 6, lane = tid & 63;
    const int wm = wave >> 1, wn = wave & 1;
    const int lr = lane & 15, lk = lane >> 4;

    const int srow = tid >> 1;          // 0..127
    const int sseg = (tid & 1) * 16;    // 0 or 16 halfs

    f32x4 acc[4][4] = {};

    for (int k0 = 0; k0 < K; k0 += 32) {
        // global loads (regs)
        const __half* ap = A + (size_t)(m0 + srow) * lda + k0 + sseg;
        ushort8 a0 = *(const ushort8*)ap;
        ushort8 a1 = *(const ushort8*)(ap + 8);
        ushort8 b0 = {0,0,0,0,0,0,0,0}, b1 = {0,0,0,0,0,0,0,0};
        if (n0 + srow < N) {
            const __half* bp = B + (size_t)(n0 + srow) * ldb + k0 + sseg;
            b0 = *(const ushort8*)bp;
            b1 = *(const ushort8*)(bp + 8);
        }
        __syncthreads();
        *(ushort8*)&As[srow * TS + sseg + 0] = a0;
        *(ushort8*)&As[srow * TS + sseg + 8] = a1;
        *(ushort8*)&Bs[srow * TS + sseg + 0] = b0;
        *(ushort8*)&Bs[srow * TS + sseg + 8] = b1;
        __syncthreads();

        half8 af[4], bf[4];
#pragma unroll
        for (int f = 0; f < 4; f++) {
            af[f] = *(const half8*)&As[(wm * 64 + f * 16 + lr) * TS + lk * 8];
            bf[f] = *(const half8*)&Bs[(wn * 64 + f * 16 + lr) * TS + lk * 8];
        }
#pragma unroll
        for (int fm = 0; fm < 4; fm++)
#pragma unroll
            for (int fn = 0; fn < 4; fn++)
                acc[fm][fn] = __builtin_amdgcn_mfma_f32_16x16x32_f16(
                    af[fm], bf[fn], acc[fm][fn], 0, 0, 0);
    }

    // epilogue: C/D map row=(lane>>4)*4+j, col=lane&15  [m89-verified]
#pragma unroll
    for (int fm = 0; fm < 4; fm++) {
#pragma unroll
        for (int fn = 0; fn < 4; fn++) {
#pragma unroll
            for (int j = 0; j < 4; j++) {
                const int gm = m0 + wm * 64 + fm * 16 + lk * 4 + j;
                const int gn = n0 + wn * 64 + fn * 16 + lr;
                if (gn >= N) continue;
                float a = acc[fm][fn][j];
                if (epi == 1) {
                    a = tanhf(a);
                    ((__half*)Cv)[(size_t)gm * ldc + gn] = __float2half(a);
                } else if (epi == 2) {
                    a += bias[gn];
                    const float xv = X[(size_t)gm * 1024 + gn];
                    float xp = 0.f;
                    if (gm & (T - 1)) xp = X[(size_t)(gm - 1) * 1024 + gn];
                    ((__half*)Cv)[(size_t)gm * ldc + gn] =
                        __float2half(xv + (xp - xv) * a);
                } else if (epi == 3) {
                    a += bias[gn];
                    ((__half*)Cv)[(size_t)gm * ldc + gn] = __float2half(a);
                } else if (epi == 4) {
                    ((float*)Cv)[(size_t)gm * ldc + gn] = a;
                } else {
                    ((__half*)Cv)[(size_t)gm * ldc + gn] = __float2half(a);
                }
            }
        }
    }
}

// ---------------- prepass: pack E = {r,k,dec} + ru --------------------------
// E layout: [b,h,t,k2] uint4 = {r0|k0<<16, dec0, r1|k1<<16, dec1}
__global__ __launch_bounds__(256) void k_prep(
    const __half* __restrict__ R, const __half* __restrict__ Kk,
    const __half* __restrict__ W, const float* __restrict__ bonus,
    uint4* __restrict__ E4, float* __restrict__ RU, int T)
{
    const int tok = blockIdx.x;
    const int b = tok >> 11, t = tok & (2048 - 1);
    const int h = threadIdx.x >> 6, lane = threadIdx.x & 63;
    const size_t base = (size_t)tok * 512 + h * 128 + 2 * lane;
    const unsigned rr = *(const unsigned*)(R + base);
    const unsigned kk = *(const unsigned*)(Kk + base);
    const unsigned ww = *(const unsigned*)(W + base);
    const float2 rf = up2(rr), kf = up2(kk), wf = up2(ww);
    const float d0 = __expf(-__expf(wf.x));
    const float d1 = __expf(-__expf(wf.y));
    const float2 uf = *(const float2*)(bonus + h * 128 + 2 * lane);
    float ru = rf.x * uf.x * kf.x + rf.y * uf.y * kf.y;
#pragma unroll
    for (int off = 1; off < 64; off <<= 1) ru += __shfl_xor(ru, off);
    const size_t eidx = ((size_t)(b * 4 + h) * T + t) * 64 + lane;  // uint4 units
    uint4 e;
    e.x = (rr & 0xFFFFu) | ((kk & 0xFFFFu) << 16);
    e.y = __float_as_uint(d0);
    e.z = (rr >> 16) | (kk & 0xFFFF0000u);
    e.w = __float_as_uint(d1);
    E4[eidx] = e;
    if (lane == 0) RU[(size_t)(b * 4 + h) * T + t] = ru;
}

// ---------------- pass 1: per-chunk state summary ---------------------------
// chunks 0..2 (chunk 3's summary unused). wave = (bh, c, vb); lane=(v,kg).
// Computes A_c[k] = prod(dec) and B_c[k,v] = chunk recurrence from S=0.
__global__ __launch_bounds__(64, 4) void rwkv_part(
    const uint4* __restrict__ E, const __half* __restrict__ V,
    float* __restrict__ Cbuf, float* __restrict__ Abuf, int T)
{
    const int p = blockIdx.x;
    const int l = (p & 7) * 384 + (p >> 3);   // 3072 blocks, bijective
    const int s = l >> 5;                     // 0..95
    const int bh = s / 3, c = s - bh * 3;
    const int vb = l & 31;
    const int lane = threadIdx.x;
    const int v = lane >> 3, kg = lane & 7;
    const int b = bh >> 2, h = bh & 3;
    const int t0 = c * 512;

    const uint4* Ep = E + ((size_t)bh * T + t0) * 64 + kg * 8;
    const __half* Vp = V + ((size_t)b * T + t0) * 1024 + h * 256 + vb * 8 + v;

    float S[16], A[16];
#pragma unroll
    for (int j = 0; j < 16; j++) { S[j] = 0.f; A[j] = 1.f; }

    uint4 eA[8], eB[8];
    float vA, vB;

#define P1_REFILL(EB, VV, TT)                                               \
    {                                                                       \
        const uint4* eb = Ep + (size_t)(TT) * 64;                           \
        _Pragma("unroll") for (int j = 0; j < 8; j++) EB[j] = eb[j];        \
        VV = __half2float(Vp[(size_t)(TT) * 1024]);                         \
    }
#define P1_COMP(EB, VV)                                                     \
    {                                                                       \
        _Pragma("unroll") for (int j = 0; j < 8; j++) {                     \
            const uint4 q = EB[j];                                          \
            const float k0 = hbits2f((unsigned short)(q.x >> 16));          \
            const float d0 = __uint_as_float(q.y);                          \
            const float k1 = hbits2f((unsigned short)(q.z >> 16));          \
            const float d1 = __uint_as_float(q.w);                          \
            S[2 * j] = fmaf(d0, S[2 * j], k0 * (VV));  A[2 * j] *= d0;      \
            S[2 * j + 1] = fmaf(d1, S[2 * j + 1], k1 * (VV));               \
            A[2 * j + 1] *= d1;                                             \
        }                                                                   \
    }

    P1_REFILL(eA, vA, 0)
    P1_REFILL(eB, vB, 1)
    for (int t = 0; t < 512; t += 2) {
        P1_COMP(eA, vA)
        if (t + 2 < 512 + 2) P1_REFILL(eA, vA, t + 2)   // t0+513 < T always (c<=2)
        P1_COMP(eB, vB)
        if (t + 3 < 512 + 2) P1_REFILL(eB, vB, t + 3)
    }
#undef P1_REFILL
#undef P1_COMP

    const int col = vb * 8 + v;
    float* Cw = Cbuf + ((size_t)c * 32 + bh) * 32768 + col;
#pragma unroll
    for (int j = 0; j < 16; j++) Cw[(size_t)(kg * 16 + j) * 256] = S[j];
    if (v == 0) {
        float* Aw = Abuf + ((size_t)c * 32 + bh) * 128 + kg * 16;
#pragma unroll
        for (int j = 0; j < 16; j++) Aw[j] = A[j];
    }
}

// ---------------- combine: C[c-1] := S_start(c) -----------------------------
__global__ __launch_bounds__(256) void rwkv_comb(
    float* __restrict__ C, const float* __restrict__ A)
{
    const int gid = blockIdx.x * 256 + threadIdx.x;   // 1M threads
    const int bh = gid >> 15;
    const int elem = gid & 32767;
    const int k = elem >> 8;
    float s = C[(size_t)bh * 32768 + elem];                       // B_0
    s = A[(size_t)(32 + bh) * 128 + k] * s +
        C[((size_t)32 + bh) * 32768 + elem];
    C[((size_t)32 + bh) * 32768 + elem] = s;                      // S_start(2)
    s = A[(size_t)(64 + bh) * 128 + k] * s +
        C[((size_t)64 + bh) * 32768 + elem];
    C[((size_t)64 + bh) * 32768 + elem] = s;                      // S_start(3)
}

// ---------------- pass 2: chunk-local scan with outputs ---------------------
// wave = (bh, c, vb); 4096 blocks -> 16 waves/CU (4/SIMD).
__global__ __launch_bounds__(64, 4) void rwkv_scan2(
    const uint4* __restrict__ E, const __half* __restrict__ V,
    const float* __restrict__ RU, const float* __restrict__ Cbuf,
    __half* __restrict__ O, int T)
{
    const int p = blockIdx.x;
    const int l = (p & 7) * 512 + (p >> 3);   // 4096 blocks, bijective
    const int bh = l >> 7, c = (l >> 5) & 3, vb = l & 31;
    const int b = bh >> 2, h = bh & 3;
    const int lane = threadIdx.x;
    const int v = lane >> 3, kg = lane & 7;
    const int t0 = c * 512;
    const int col = vb * 8 + v;

    const uint4* Ep = E + ((size_t)bh * T + t0) * 64 + kg * 8;
    const float* RUp = RU + (size_t)bh * T + t0;
    const __half* Vp = V + ((size_t)b * T + t0) * 1024 + h * 256 + col;
    __half* Op = O + ((size_t)b * T + t0) * 1024 + h * 256 + col;

    float S[16];
    if (c == 0) {
#pragma unroll
        for (int j = 0; j < 16; j++) S[j] = 0.f;
    } else {
        const float* Sp = Cbuf + ((size_t)(c - 1) * 32 + bh) * 32768 + col;
#pragma unroll
        for (int j = 0; j < 16; j++) S[j] = Sp[(size_t)(kg * 16 + j) * 256];
    }

    uint4 eA[8], eB[8];
    float vA, vB, ruA, ruB;

#define P2_REFILL(EB, VV, RR, TT)                                           \
    {                                                                       \
        const uint4* eb = Ep + (size_t)(TT) * 64;                           \
        _Pragma("unroll") for (int j = 0; j < 8; j++) EB[j] = eb[j];        \
        VV = __half2float(Vp[(size_t)(TT) * 1024]);                         \
        RR = RUp[TT];                                                       \
    }
#define P2_COMP(EB, VV, RR, TT)                                             \
    {                                                                       \
        float osum = 0.f;                                                   \
        _Pragma("unroll") for (int j = 0; j < 8; j++) {                     \
            const uint4 q = EB[j];                                          \
            const float2 rk0 = up2(q.x);                                    \
            const float d0 = __uint_as_float(q.y);                          \
            const float2 rk1 = up2(q.z);                                    \
            const float d1 = __uint_as_float(q.w);                          \
            osum = fmaf(rk0.x, S[2 * j], osum);                             \
            S[2 * j] = fmaf(d0, S[2 * j], rk0.y * (VV));                    \
            osum = fmaf(rk1.x, S[2 * j + 1], osum);                         \
            S[2 * j + 1] = fmaf(d1, S[2 * j + 1], rk1.y * (VV));            \
        }                                                                   \
        osum += __shfl_xor(osum, 1);                                        \
        osum += __shfl_xor(osum, 2);                                        \
        osum += __shfl_xor(osum, 4);                                        \
        if (kg == 0) Op[(size_t)(TT) * 1024] = __float2half(osum + (RR) * (VV)); \
    }

    P2_REFILL(eA, vA, ruA, 0)
    P2_REFILL(eB, vB, ruB, 1)
    for (int t = 0; t < 512; t += 2) {
        P2_COMP(eA, vA, ruA, t)
        if (t0 + t + 2 < T) P2_REFILL(eA, vA, ruA, t + 2)
        P2_COMP(eB, vB, ruB, t + 1)
        if (t0 + t + 3 < T) P2_REFILL(eB, vB, ruB, t + 3)
    }
#undef P2_REFILL
#undef P2_COMP
}

// ---------------- groupnorm + silu gate (f16 in/out) ------------------------
__global__ __launch_bounds__(256) void gn_gate(
    const __half* __restrict__ Obuf, const __half* __restrict__ G,
    const float* __restrict__ gnw, const float* __restrict__ gnb,
    __half* __restrict__ Y)
{
    const int token = blockIdx.x;
    const int wave = threadIdx.x >> 6, lane = threadIdx.x & 63;
    const size_t base = (size_t)token * 1024 + wave * 256 + lane * 4;
    const ushort4 xu = *(const ushort4*)(Obuf + base);
    const float x0 = hbits2f(xu.x), x1 = hbits2f(xu.y),
                x2 = hbits2f(xu.z), x3 = hbits2f(xu.w);
    float sum = x0 + x1 + x2 + x3;
    float ssq = x0 * x0 + x1 * x1 + x2 * x2 + x3 * x3;
#pragma unroll
    for (int off = 32; off >= 1; off >>= 1) {
        sum += __shfl_xor(sum, off);
        ssq += __shfl_xor(ssq, off);
    }
    const float mean = sum * (1.f / 256.f);
    const float var = ssq * (1.f / 256.f) - mean * mean;
    const float rstd = rsqrtf(var + 1e-5f);
    const int c0 = wave * 256 + lane * 4;
    const float4 w4 = *(const float4*)(gnw + c0);
    const float4 b4 = *(const float4*)(gnb + c0);
    const ushort4 gu = *(const ushort4*)(G + base);
    const float g0 = hbits2f(gu.x), g1 = hbits2f(gu.y),
                g2 = hbits2f(gu.z), g3 = hbits2f(gu.w);
    ushort4 y;
    y.x = f2h(((x0 - mean) * rstd * w4.x + b4.x) * (g0 / (1.f + __expf(-g0))));
    y.y = f2h(((x1 - mean) * rstd * w4.y + b4.y) * (g1 / (1.f + __expf(-g1))));
    y.z = f2h(((x2 - mean) * rstd * w4.z + b4.z) * (g2 / (1.f + __expf(-g2))));
    y.w = f2h(((x3 - mean) * rstd * w4.w + b4.w) * (g3 / (1.f + __expf(-g3))));
    *(ushort4*)(Y + base) = y;
}

// ---------------------------------------------------------------------------
extern "C" void kernel_launch(void* const* d_in, const int* in_sizes, int n_in,
                              void* d_out, int out_size, void* d_ws, size_t ws_size,
                              hipStream_t stream)
{
    (void)in_sizes; (void)n_in; (void)out_size; (void)ws_size;
    const float* x      = (const float*)d_in[0];
    const float* mu_x   = (const float*)d_in[1];
    const float* W_x1   = (const float*)d_in[2];
    const float* W_x2   = (const float*)d_in[3];
    const float* x_bias = (const float*)d_in[4];
    const float* W_r    = (const float*)d_in[5];
    const float* W_k    = (const float*)d_in[6];
    const float* W_v    = (const float*)d_in[7];
    const float* W_g    = (const float*)d_in[8];
    const float* A_w    = (const float*)d_in[9];
    const float* B_w    = (const float*)d_in[10];
    const float* b_w    = (const float*)d_in[11];
    const float* bonus  = (const float*)d_in[12];
    const float* gnw    = (const float*)d_in[13];
    const float* gnb    = (const float*)d_in[14];
    const float* W_o    = (const float*)d_in[15];

    const int B = 8, T = 2048, M = B * T;

    // ---- d_out as f16 scratch: [xw_h 32MB | inb_h 32MB], later E (64MB) ----
    __half* xwh  = (__half*)d_out;
    __half* inbh = xwh + (size_t)M * 1024;

    // ---- ws layout (halfs unless noted) ----
    __half* z   = (__half*)d_ws;                    // M*160
    __half* w1  = z   + (size_t)M * 160;            // M*64
    __half* rs  = w1  + (size_t)M * 64;             // M*512
    __half* ks  = rs  + (size_t)M * 512;            // M*512
    __half* wsm = ks  + (size_t)M * 512;            // M*512 (w stream)
    __half* vs  = wsm + (size_t)M * 512;            // M*1024
    __half* gs  = vs  + (size_t)M * 1024;           // M*1024
    float*  ru  = (float*)(gs + (size_t)M * 1024);  // 32*T f32
    __half* wgt = (__half*)(ru + (size_t)32 * T);   // f16 weights
    __half* oh  = rs;                               // overlay: o f16 M*1024 (r+k dead)
    __half* yb  = wsm;                              // overlay: y f16 (w+v dead post-scan)
    float*  Cbuf = (float*)wsm;                     // overlay: 3*32*32768 f32 = 12.6MB
    float*  Abuf = (float*)z;                       // overlay: 3*32*128 f32 (z dead)

    __half* W_x1h = wgt;                 // 160*1024
    __half* W_x2h = W_x1h + 163840;      // 1024*160
    __half* W_rh  = W_x2h + 163840;      // 512*1024
    __half* W_kh  = W_rh + 524288;
    __half* W_vh  = W_kh + 524288;       // 1024*1024
    __half* W_gh  = W_vh + 1048576;
    __half* A_wh  = W_gh + 1048576;      // 64*1024
    __half* B_wh  = A_wh + 65536;        // 512*64
    __half* W_oh  = B_wh + 32768;        // 1024*1024

    const dim3 blk(256);
    auto cgrid = [](int n) { return dim3((n / 4 + 255) / 256); };
    cast16<<<cgrid(163840), blk, 0, stream>>>(W_x1, W_x1h, 163840 / 4);
    cast16<<<cgrid(163840), blk, 0, stream>>>(W_x2, W_x2h, 163840 / 4);
    cast16<<<cgrid(524288), blk, 0, stream>>>(W_r, W_rh, 524288 / 4);
    cast16<<<cgrid(524288), blk, 0, stream>>>(W_k, W_kh, 524288 / 4);
    cast16<<<cgrid(1048576), blk, 0, stream>>>(W_v, W_vh, 1048576 / 4);
    cast16<<<cgrid(1048576), blk, 0, stream>>>(W_g, W_gh, 1048576 / 4);
    cast16<<<cgrid(65536), blk, 0, stream>>>(A_w, A_wh, 65536 / 4);
    cast16<<<cgrid(32768), blk, 0, stream>>>(B_w, B_wh, 32768 / 4);
    cast16<<<cgrid(1048576), blk, 0, stream>>>(W_o, W_oh, 1048576 / 4);

    // 1. xw = lerp(x, mu_x) -> f16 (d_out lo)
    k_xw_h<<<(M * 256 + 255) / 256, blk, 0, stream>>>(x, mu_x, xwh, M, T);

    auto ggrid = [&](int N) { return dim3((N + 127) / 128, M / 128); };

    // 2. z = tanh(xw @ W_x1^T)
    gemm16<<<ggrid(160), blk, 0, stream>>>(xwh, 1024, W_x1h, 1024, z, 160,
                                           M, 160, 1024, nullptr, 1, nullptr, T);

    // 3. branches
    for (int n = 0; n < 5; ++n) {
        gemm16<<<ggrid(1024), blk, 0, stream>>>(z + n * 32, 160, W_x2h + n * 32, 160,
                                                inbh, 1024, M, 1024, 32,
                                                x_bias + n * 1024, 2, x, T);
        if (n == 1) {
            gemm16<<<ggrid(64), blk, 0, stream>>>(inbh, 1024, A_wh, 1024, w1, 64,
                                                  M, 64, 1024, nullptr, 1, nullptr, T);
            gemm16<<<ggrid(512), blk, 0, stream>>>(w1, 64, B_wh, 64, wsm, 512,
                                                   M, 512, 64, b_w, 3, nullptr, T);
        } else {
            __half* Cp = (n == 0) ? rs : (n == 2) ? ks : (n == 3) ? vs : gs;
            const __half* Wp = (n == 0) ? W_rh : (n == 2) ? W_kh : (n == 3) ? W_vh : W_gh;
            const int N = (n == 0 || n == 2) ? 512 : 1024;
            gemm16<<<ggrid(N), blk, 0, stream>>>(inbh, 1024, Wp, 1024, Cp, N,
                                                 M, N, 1024, nullptr, 0, nullptr, T);
        }
    }

    // 4. prepass -> E (all of d_out; xwh/inbh dead), ru
    k_prep<<<dim3(M), blk, 0, stream>>>(rs, ks, wsm, bonus,
                                        (uint4*)d_out, ru, T);

    // 5a. chunk summaries (chunks 0..2) -> Cbuf (overlays dead wsm), Abuf
    rwkv_part<<<dim3(3072), dim3(64), 0, stream>>>((const uint4*)d_out, vs,
                                                   Cbuf, Abuf, T);
    // 5b. combine -> Cbuf[c-1] = S_start(c)
    rwkv_comb<<<dim3(4096), blk, 0, stream>>>(Cbuf, Abuf);
    // 5c. chunk-local scan with outputs -> o f16 (overlay on r+k region)
    rwkv_scan2<<<dim3(4096), dim3(64), 0, stream>>>((const uint4*)d_out, vs, ru,
                                                    Cbuf, oh, T);

    // 6. groupnorm + gate -> yb f16 (overlay on w+v region; Cbuf dead)
    gn_gate<<<dim3(M), blk, 0, stream>>>(oh, gs, gnw, gnb, yb);

    // 7. out = y @ W_o^T -> d_out f32 (E dead)
    gemm16<<<ggrid(1024), blk, 0, stream>>>(yb, 1024, W_oh, 1024, d_out, 1024,
                                            M, 1024, 1024, nullptr, 4, nullptr, T);
}

// Round 8
// 3963.135 us; speedup vs baseline: 2.1926x; 2.1926x over previous
//
#include <hip/hip_runtime.h>
#include <hip/hip_bf16.h>
#include <hip/hip_fp16.h>
#include <cstdint>

// ---------------------------------------------------------------------------
// RWKV6 attention: f16-MFMA GEMMs + chunked parallel scan.
//   Round 8: fix round-7 spill — __launch_bounds__(64,4) had capped VGPR=64
//   (2nd arg = min waves/EU) and spilled the prefetch buffers (18GB scratch
//   writes). Plain __launch_bounds__(64) -> ~105 VGPR, still 4 waves/SIMD.
// ---------------------------------------------------------------------------

typedef _Float16 half8 __attribute__((ext_vector_type(8)));
typedef float f32x4 __attribute__((ext_vector_type(4)));
typedef unsigned short ushort8 __attribute__((ext_vector_type(8)));

__device__ __forceinline__ float hbits2f(unsigned short us) {
    __half h; *reinterpret_cast<unsigned short*>(&h) = us; return __half2float(h);
}
__device__ __forceinline__ unsigned short f2h(float f) {
    __half h = __float2half(f);
    return *reinterpret_cast<unsigned short*>(&h);
}
__device__ __forceinline__ float2 up2(unsigned int u) {
    return make_float2(hbits2f((unsigned short)(u & 0xFFFF)),
                       hbits2f((unsigned short)(u >> 16)));
}

// ---------------- generic f32 -> f16 cast (weights) -------------------------
__global__ void cast16(const float* __restrict__ src, __half* __restrict__ dst, int n4)
{
    const int i = blockIdx.x * blockDim.x + threadIdx.x;
    if (i >= n4) return;
    const float4 f = *(const float4*)(src + (size_t)i * 4);
    ushort4 u;
    u.x = f2h(f.x); u.y = f2h(f.y); u.z = f2h(f.z); u.w = f2h(f.w);
    *(ushort4*)(dst + (size_t)i * 4) = u;
}

// ---------------- token shift (f16 out) -------------------------------------
__global__ void k_xw_h(const float* __restrict__ X, const float* __restrict__ mu,
                       __half* __restrict__ XW, int M, int T)
{
    const size_t i4 = (size_t)blockIdx.x * blockDim.x + threadIdx.x;
    if (i4 >= (size_t)M * 256) return;
    const size_t idx = i4 * 4;
    const int m = (int)(idx >> 10);
    const int d = (int)(idx & 1023);
    const int t = m & (T - 1);
    const float4 xv = *(const float4*)(X + idx);
    const float4 m4 = *(const float4*)(mu + d);
    float4 xp = make_float4(0.f, 0.f, 0.f, 0.f);
    if (t > 0) xp = *(const float4*)(X + idx - 1024);
    ushort4 o;
    o.x = f2h(xv.x + (xp.x - xv.x) * m4.x);
    o.y = f2h(xv.y + (xp.y - xv.y) * m4.y);
    o.z = f2h(xv.z + (xp.z - xv.z) * m4.z);
    o.w = f2h(xv.w + (xp.w - xv.w) * m4.w);
    *(ushort4*)(XW + idx) = o;
}

// ---------------- f16 MFMA GEMM: C[M,N] = A[M,K] @ B[N,K]^T -----------------
// epi: 0 f16 plain, 1 f16 tanh, 2 f16 bias+delta-lerp(X), 3 f16 bias, 4 f32 plain
#define TS 40  // LDS row stride in halfs (padded from 32)

__global__ __launch_bounds__(256) void gemm16(
    const __half* __restrict__ A, int lda,
    const __half* __restrict__ B, int ldb,
    void* __restrict__ Cv, int ldc,
    int M, int N, int K,
    const float* __restrict__ bias, int epi,
    const float* __restrict__ X, int T)
{
    __shared__ __align__(16) _Float16 As[128 * TS];
    __shared__ __align__(16) _Float16 Bs[128 * TS];

    const int tid = threadIdx.x;

    // XCD-aware swizzle: consecutive logical blocks (same A-row panel) on one XCD
    const int nwg = gridDim.x * gridDim.y;
    int p = blockIdx.y * gridDim.x + blockIdx.x;
    if (!(nwg & 7)) p = (p & 7) * (nwg >> 3) + (p >> 3);
    const int bx = p % gridDim.x, by = p / gridDim.x;

    const int m0 = by * 128;
    const int n0 = bx * 128;
    const int wave = tid >> 6, lane = tid & 63;
    const int wm = wave >> 1, wn = wave & 1;
    const int lr = lane & 15, lk = lane >> 4;

    const int srow = tid >> 1;          // 0..127
    const int sseg = (tid & 1) * 16;    // 0 or 16 halfs

    f32x4 acc[4][4] = {};

    for (int k0 = 0; k0 < K; k0 += 32) {
        // global loads (regs)
        const __half* ap = A + (size_t)(m0 + srow) * lda + k0 + sseg;
        ushort8 a0 = *(const ushort8*)ap;
        ushort8 a1 = *(const ushort8*)(ap + 8);
        ushort8 b0 = {0,0,0,0,0,0,0,0}, b1 = {0,0,0,0,0,0,0,0};
        if (n0 + srow < N) {
            const __half* bp = B + (size_t)(n0 + srow) * ldb + k0 + sseg;
            b0 = *(const ushort8*)bp;
            b1 = *(const ushort8*)(bp + 8);
        }
        __syncthreads();
        *(ushort8*)&As[srow * TS + sseg + 0] = a0;
        *(ushort8*)&As[srow * TS + sseg + 8] = a1;
        *(ushort8*)&Bs[srow * TS + sseg + 0] = b0;
        *(ushort8*)&Bs[srow * TS + sseg + 8] = b1;
        __syncthreads();

        half8 af[4], bf[4];
#pragma unroll
        for (int f = 0; f < 4; f++) {
            af[f] = *(const half8*)&As[(wm * 64 + f * 16 + lr) * TS + lk * 8];
            bf[f] = *(const half8*)&Bs[(wn * 64 + f * 16 + lr) * TS + lk * 8];
        }
#pragma unroll
        for (int fm = 0; fm < 4; fm++)
#pragma unroll
            for (int fn = 0; fn < 4; fn++)
                acc[fm][fn] = __builtin_amdgcn_mfma_f32_16x16x32_f16(
                    af[fm], bf[fn], acc[fm][fn], 0, 0, 0);
    }

    // epilogue: C/D map row=(lane>>4)*4+j, col=lane&15  [m89-verified]
#pragma unroll
    for (int fm = 0; fm < 4; fm++) {
#pragma unroll
        for (int fn = 0; fn < 4; fn++) {
#pragma unroll
            for (int j = 0; j < 4; j++) {
                const int gm = m0 + wm * 64 + fm * 16 + lk * 4 + j;
                const int gn = n0 + wn * 64 + fn * 16 + lr;
                if (gn >= N) continue;
                float a = acc[fm][fn][j];
                if (epi == 1) {
                    a = tanhf(a);
                    ((__half*)Cv)[(size_t)gm * ldc + gn] = __float2half(a);
                } else if (epi == 2) {
                    a += bias[gn];
                    const float xv = X[(size_t)gm * 1024 + gn];
                    float xp = 0.f;
                    if (gm & (T - 1)) xp = X[(size_t)(gm - 1) * 1024 + gn];
                    ((__half*)Cv)[(size_t)gm * ldc + gn] =
                        __float2half(xv + (xp - xv) * a);
                } else if (epi == 3) {
                    a += bias[gn];
                    ((__half*)Cv)[(size_t)gm * ldc + gn] = __float2half(a);
                } else if (epi == 4) {
                    ((float*)Cv)[(size_t)gm * ldc + gn] = a;
                } else {
                    ((__half*)Cv)[(size_t)gm * ldc + gn] = __float2half(a);
                }
            }
        }
    }
}

// ---------------- prepass: pack E = {r,k,dec} + ru --------------------------
// E layout: [b,h,t,k2] uint4 = {r0|k0<<16, dec0, r1|k1<<16, dec1}
__global__ __launch_bounds__(256) void k_prep(
    const __half* __restrict__ R, const __half* __restrict__ Kk,
    const __half* __restrict__ W, const float* __restrict__ bonus,
    uint4* __restrict__ E4, float* __restrict__ RU, int T)
{
    const int tok = blockIdx.x;
    const int b = tok >> 11, t = tok & (2048 - 1);
    const int h = threadIdx.x >> 6, lane = threadIdx.x & 63;
    const size_t base = (size_t)tok * 512 + h * 128 + 2 * lane;
    const unsigned rr = *(const unsigned*)(R + base);
    const unsigned kk = *(const unsigned*)(Kk + base);
    const unsigned ww = *(const unsigned*)(W + base);
    const float2 rf = up2(rr), kf = up2(kk), wf = up2(ww);
    const float d0 = __expf(-__expf(wf.x));
    const float d1 = __expf(-__expf(wf.y));
    const float2 uf = *(const float2*)(bonus + h * 128 + 2 * lane);
    float ru = rf.x * uf.x * kf.x + rf.y * uf.y * kf.y;
#pragma unroll
    for (int off = 1; off < 64; off <<= 1) ru += __shfl_xor(ru, off);
    const size_t eidx = ((size_t)(b * 4 + h) * T + t) * 64 + lane;  // uint4 units
    uint4 e;
    e.x = (rr & 0xFFFFu) | ((kk & 0xFFFFu) << 16);
    e.y = __float_as_uint(d0);
    e.z = (rr >> 16) | (kk & 0xFFFF0000u);
    e.w = __float_as_uint(d1);
    E4[eidx] = e;
    if (lane == 0) RU[(size_t)(b * 4 + h) * T + t] = ru;
}

// ---------------- pass 1: per-chunk state summary ---------------------------
// chunks 0..2 (chunk 3's summary unused). wave = (bh, c, vb); lane=(v,kg).
// Computes A_c[k] = prod(dec) and B_c[k,v] = chunk recurrence from S=0.
__global__ __launch_bounds__(64) void rwkv_part(
    const uint4* __restrict__ E, const __half* __restrict__ V,
    float* __restrict__ Cbuf, float* __restrict__ Abuf, int T)
{
    const int p = blockIdx.x;
    const int l = (p & 7) * 384 + (p >> 3);   // 3072 blocks, bijective
    const int s = l >> 5;                     // 0..95
    const int bh = s / 3, c = s - bh * 3;
    const int vb = l & 31;
    const int lane = threadIdx.x;
    const int v = lane >> 3, kg = lane & 7;
    const int b = bh >> 2, h = bh & 3;
    const int t0 = c * 512;

    const uint4* Ep = E + ((size_t)bh * T + t0) * 64 + kg * 8;
    const __half* Vp = V + ((size_t)b * T + t0) * 1024 + h * 256 + vb * 8 + v;

    float S[16], A[16];
#pragma unroll
    for (int j = 0; j < 16; j++) { S[j] = 0.f; A[j] = 1.f; }

    uint4 eA[8], eB[8];
    float vA, vB;

#define P1_REFILL(EB, VV, TT)                                               \
    {                                                                       \
        const uint4* eb = Ep + (size_t)(TT) * 64;                           \
        _Pragma("unroll") for (int j = 0; j < 8; j++) EB[j] = eb[j];        \
        VV = __half2float(Vp[(size_t)(TT) * 1024]);                         \
    }
#define P1_COMP(EB, VV)                                                     \
    {                                                                       \
        _Pragma("unroll") for (int j = 0; j < 8; j++) {                     \
            const uint4 q = EB[j];                                          \
            const float k0 = hbits2f((unsigned short)(q.x >> 16));          \
            const float d0 = __uint_as_float(q.y);                          \
            const float k1 = hbits2f((unsigned short)(q.z >> 16));          \
            const float d1 = __uint_as_float(q.w);                          \
            S[2 * j] = fmaf(d0, S[2 * j], k0 * (VV));  A[2 * j] *= d0;      \
            S[2 * j + 1] = fmaf(d1, S[2 * j + 1], k1 * (VV));               \
            A[2 * j + 1] *= d1;                                             \
        }                                                                   \
    }

    P1_REFILL(eA, vA, 0)
    P1_REFILL(eB, vB, 1)
    for (int t = 0; t < 512; t += 2) {
        P1_COMP(eA, vA)
        if (t + 2 < 512 + 2) P1_REFILL(eA, vA, t + 2)   // t0+513 < T always (c<=2)
        P1_COMP(eB, vB)
        if (t + 3 < 512 + 2) P1_REFILL(eB, vB, t + 3)
    }
#undef P1_REFILL
#undef P1_COMP

    const int col = vb * 8 + v;
    float* Cw = Cbuf + ((size_t)c * 32 + bh) * 32768 + col;
#pragma unroll
    for (int j = 0; j < 16; j++) Cw[(size_t)(kg * 16 + j) * 256] = S[j];
    if (v == 0) {
        float* Aw = Abuf + ((size_t)c * 32 + bh) * 128 + kg * 16;
#pragma unroll
        for (int j = 0; j < 16; j++) Aw[j] = A[j];
    }
}

// ---------------- combine: C[c-1] := S_start(c) -----------------------------
__global__ __launch_bounds__(256) void rwkv_comb(
    float* __restrict__ C, const float* __restrict__ A)
{
    const int gid = blockIdx.x * 256 + threadIdx.x;   // 1M threads
    const int bh = gid >> 15;
    const int elem = gid & 32767;
    const int k = elem >> 8;
    float s = C[(size_t)bh * 32768 + elem];                       // B_0
    s = A[(size_t)(32 + bh) * 128 + k] * s +
        C[((size_t)32 + bh) * 32768 + elem];
    C[((size_t)32 + bh) * 32768 + elem] = s;                      // S_start(2)
    s = A[(size_t)(64 + bh) * 128 + k] * s +
        C[((size_t)64 + bh) * 32768 + elem];
    C[((size_t)64 + bh) * 32768 + elem] = s;                      // S_start(3)
}

// ---------------- pass 2: chunk-local scan with outputs ---------------------
// wave = (bh, c, vb); 4096 blocks -> 16 waves/CU (4/SIMD).
__global__ __launch_bounds__(64) void rwkv_scan2(
    const uint4* __restrict__ E, const __half* __restrict__ V,
    const float* __restrict__ RU, const float* __restrict__ Cbuf,
    __half* __restrict__ O, int T)
{
    const int p = blockIdx.x;
    const int l = (p & 7) * 512 + (p >> 3);   // 4096 blocks, bijective
    const int bh = l >> 7, c = (l >> 5) & 3, vb = l & 31;
    const int b = bh >> 2, h = bh & 3;
    const int lane = threadIdx.x;
    const int v = lane >> 3, kg = lane & 7;
    const int t0 = c * 512;
    const int col = vb * 8 + v;

    const uint4* Ep = E + ((size_t)bh * T + t0) * 64 + kg * 8;
    const float* RUp = RU + (size_t)bh * T + t0;
    const __half* Vp = V + ((size_t)b * T + t0) * 1024 + h * 256 + col;
    __half* Op = O + ((size_t)b * T + t0) * 1024 + h * 256 + col;

    float S[16];
    if (c == 0) {
#pragma unroll
        for (int j = 0; j < 16; j++) S[j] = 0.f;
    } else {
        const float* Sp = Cbuf + ((size_t)(c - 1) * 32 + bh) * 32768 + col;
#pragma unroll
        for (int j = 0; j < 16; j++) S[j] = Sp[(size_t)(kg * 16 + j) * 256];
    }

    uint4 eA[8], eB[8];
    float vA, vB, ruA, ruB;

#define P2_REFILL(EB, VV, RR, TT)                                           \
    {                                                                       \
        const uint4* eb = Ep + (size_t)(TT) * 64;                           \
        _Pragma("unroll") for (int j = 0; j < 8; j++) EB[j] = eb[j];        \
        VV = __half2float(Vp[(size_t)(TT) * 1024]);                         \
        RR = RUp[TT];                                                       \
    }
#define P2_COMP(EB, VV, RR, TT)                                             \
    {                                                                       \
        float osum = 0.f;                                                   \
        _Pragma("unroll") for (int j = 0; j < 8; j++) {                     \
            const uint4 q = EB[j];                                          \
            const float2 rk0 = up2(q.x);                                    \
            const float d0 = __uint_as_float(q.y);                          \
            const float2 rk1 = up2(q.z);                                    \
            const float d1 = __uint_as_float(q.w);                          \
            osum = fmaf(rk0.x, S[2 * j], osum);                             \
            S[2 * j] = fmaf(d0, S[2 * j], rk0.y * (VV));                    \
            osum = fmaf(rk1.x, S[2 * j + 1], osum);                         \
            S[2 * j + 1] = fmaf(d1, S[2 * j + 1], rk1.y * (VV));            \
        }                                                                   \
        osum += __shfl_xor(osum, 1);                                        \
        osum += __shfl_xor(osum, 2);                                        \
        osum += __shfl_xor(osum, 4);                                        \
        if (kg == 0) Op[(size_t)(TT) * 1024] = __float2half(osum + (RR) * (VV)); \
    }

    P2_REFILL(eA, vA, ruA, 0)
    P2_REFILL(eB, vB, ruB, 1)
    for (int t = 0; t < 512; t += 2) {
        P2_COMP(eA, vA, ruA, t)
        if (t0 + t + 2 < T) P2_REFILL(eA, vA, ruA, t + 2)
        P2_COMP(eB, vB, ruB, t + 1)
        if (t0 + t + 3 < T) P2_REFILL(eB, vB, ruB, t + 3)
    }
#undef P2_REFILL
#undef P2_COMP
}

// ---------------- groupnorm + silu gate (f16 in/out) ------------------------
__global__ __launch_bounds__(256) void gn_gate(
    const __half* __restrict__ Obuf, const __half* __restrict__ G,
    const float* __restrict__ gnw, const float* __restrict__ gnb,
    __half* __restrict__ Y)
{
    const int token = blockIdx.x;
    const int wave = threadIdx.x >> 6, lane = threadIdx.x & 63;
    const size_t base = (size_t)token * 1024 + wave * 256 + lane * 4;
    const ushort4 xu = *(const ushort4*)(Obuf + base);
    const float x0 = hbits2f(xu.x), x1 = hbits2f(xu.y),
                x2 = hbits2f(xu.z), x3 = hbits2f(xu.w);
    float sum = x0 + x1 + x2 + x3;
    float ssq = x0 * x0 + x1 * x1 + x2 * x2 + x3 * x3;
#pragma unroll
    for (int off = 32; off >= 1; off >>= 1) {
        sum += __shfl_xor(sum, off);
        ssq += __shfl_xor(ssq, off);
    }
    const float mean = sum * (1.f / 256.f);
    const float var = ssq * (1.f / 256.f) - mean * mean;
    const float rstd = rsqrtf(var + 1e-5f);
    const int c0 = wave * 256 + lane * 4;
    const float4 w4 = *(const float4*)(gnw + c0);
    const float4 b4 = *(const float4*)(gnb + c0);
    const ushort4 gu = *(const ushort4*)(G + base);
    const float g0 = hbits2f(gu.x), g1 = hbits2f(gu.y),
                g2 = hbits2f(gu.z), g3 = hbits2f(gu.w);
    ushort4 y;
    y.x = f2h(((x0 - mean) * rstd * w4.x + b4.x) * (g0 / (1.f + __expf(-g0))));
    y.y = f2h(((x1 - mean) * rstd * w4.y + b4.y) * (g1 / (1.f + __expf(-g1))));
    y.z = f2h(((x2 - mean) * rstd * w4.z + b4.z) * (g2 / (1.f + __expf(-g2))));
    y.w = f2h(((x3 - mean) * rstd * w4.w + b4.w) * (g3 / (1.f + __expf(-g3))));
    *(ushort4*)(Y + base) = y;
}

// ---------------------------------------------------------------------------
extern "C" void kernel_launch(void* const* d_in, const int* in_sizes, int n_in,
                              void* d_out, int out_size, void* d_ws, size_t ws_size,
                              hipStream_t stream)
{
    (void)in_sizes; (void)n_in; (void)out_size; (void)ws_size;
    const float* x      = (const float*)d_in[0];
    const float* mu_x   = (const float*)d_in[1];
    const float* W_x1   = (const float*)d_in[2];
    const float* W_x2   = (const float*)d_in[3];
    const float* x_bias = (const float*)d_in[4];
    const float* W_r    = (const float*)d_in[5];
    const float* W_k    = (const float*)d_in[6];
    const float* W_v    = (const float*)d_in[7];
    const float* W_g    = (const float*)d_in[8];
    const float* A_w    = (const float*)d_in[9];
    const float* B_w    = (const float*)d_in[10];
    const float* b_w    = (const float*)d_in[11];
    const float* bonus  = (const float*)d_in[12];
    const float* gnw    = (const float*)d_in[13];
    const float* gnb    = (const float*)d_in[14];
    const float* W_o    = (const float*)d_in[15];

    const int B = 8, T = 2048, M = B * T;

    // ---- d_out as f16 scratch: [xw_h 32MB | inb_h 32MB], later E (64MB) ----
    __half* xwh  = (__half*)d_out;
    __half* inbh = xwh + (size_t)M * 1024;

    // ---- ws layout (halfs unless noted) ----
    __half* z   = (__half*)d_ws;                    // M*160
    __half* w1  = z   + (size_t)M * 160;            // M*64
    __half* rs  = w1  + (size_t)M * 64;             // M*512
    __half* ks  = rs  + (size_t)M * 512;            // M*512
    __half* wsm = ks  + (size_t)M * 512;            // M*512 (w stream)
    __half* vs  = wsm + (size_t)M * 512;            // M*1024
    __half* gs  = vs  + (size_t)M * 1024;           // M*1024
    float*  ru  = (float*)(gs + (size_t)M * 1024);  // 32*T f32
    __half* wgt = (__half*)(ru + (size_t)32 * T);   // f16 weights
    __half* oh  = rs;                               // overlay: o f16 M*1024 (r+k dead)
    __half* yb  = wsm;                              // overlay: y f16 (w+v dead post-scan)
    float*  Cbuf = (float*)wsm;                     // overlay: 3*32*32768 f32 = 12.6MB
    float*  Abuf = (float*)z;                       // overlay: 3*32*128 f32 (z dead)

    __half* W_x1h = wgt;                 // 160*1024
    __half* W_x2h = W_x1h + 163840;      // 1024*160
    __half* W_rh  = W_x2h + 163840;      // 512*1024
    __half* W_kh  = W_rh + 524288;
    __half* W_vh  = W_kh + 524288;       // 1024*1024
    __half* W_gh  = W_vh + 1048576;
    __half* A_wh  = W_gh + 1048576;      // 64*1024
    __half* B_wh  = A_wh + 65536;        // 512*64
    __half* W_oh  = B_wh + 32768;        // 1024*1024

    const dim3 blk(256);
    auto cgrid = [](int n) { return dim3((n / 4 + 255) / 256); };
    cast16<<<cgrid(163840), blk, 0, stream>>>(W_x1, W_x1h, 163840 / 4);
    cast16<<<cgrid(163840), blk, 0, stream>>>(W_x2, W_x2h, 163840 / 4);
    cast16<<<cgrid(524288), blk, 0, stream>>>(W_r, W_rh, 524288 / 4);
    cast16<<<cgrid(524288), blk, 0, stream>>>(W_k, W_kh, 524288 / 4);
    cast16<<<cgrid(1048576), blk, 0, stream>>>(W_v, W_vh, 1048576 / 4);
    cast16<<<cgrid(1048576), blk, 0, stream>>>(W_g, W_gh, 1048576 / 4);
    cast16<<<cgrid(65536), blk, 0, stream>>>(A_w, A_wh, 65536 / 4);
    cast16<<<cgrid(32768), blk, 0, stream>>>(B_w, B_wh, 32768 / 4);
    cast16<<<cgrid(1048576), blk, 0, stream>>>(W_o, W_oh, 1048576 / 4);

    // 1. xw = lerp(x, mu_x) -> f16 (d_out lo)
    k_xw_h<<<(M * 256 + 255) / 256, blk, 0, stream>>>(x, mu_x, xwh, M, T);

    auto ggrid = [&](int N) { return dim3((N + 127) / 128, M / 128); };

    // 2. z = tanh(xw @ W_x1^T)
    gemm16<<<ggrid(160), blk, 0, stream>>>(xwh, 1024, W_x1h, 1024, z, 160,
                                           M, 160, 1024, nullptr, 1, nullptr, T);

    // 3. branches
    for (int n = 0; n < 5; ++n) {
        gemm16<<<ggrid(1024), blk, 0, stream>>>(z + n * 32, 160, W_x2h + n * 32, 160,
                                                inbh, 1024, M, 1024, 32,
                                                x_bias + n * 1024, 2, x, T);
        if (n == 1) {
            gemm16<<<ggrid(64), blk, 0, stream>>>(inbh, 1024, A_wh, 1024, w1, 64,
                                                  M, 64, 1024, nullptr, 1, nullptr, T);
            gemm16<<<ggrid(512), blk, 0, stream>>>(w1, 64, B_wh, 64, wsm, 512,
                                                   M, 512, 64, b_w, 3, nullptr, T);
        } else {
            __half* Cp = (n == 0) ? rs : (n == 2) ? ks : (n == 3) ? vs : gs;
            const __half* Wp = (n == 0) ? W_rh : (n == 2) ? W_kh : (n == 3) ? W_vh : W_gh;
            const int N = (n == 0 || n == 2) ? 512 : 1024;
            gemm16<<<ggrid(N), blk, 0, stream>>>(inbh, 1024, Wp, 1024, Cp, N,
                                                 M, N, 1024, nullptr, 0, nullptr, T);
        }
    }

    // 4. prepass -> E (all of d_out; xwh/inbh dead), ru
    k_prep<<<dim3(M), blk, 0, stream>>>(rs, ks, wsm, bonus,
                                        (uint4*)d_out, ru, T);

    // 5a. chunk summaries (chunks 0..2) -> Cbuf (overlays dead wsm), Abuf
    rwkv_part<<<dim3(3072), dim3(64), 0, stream>>>((const uint4*)d_out, vs,
                                                   Cbuf, Abuf, T);
    // 5b. combine -> Cbuf[c-1] = S_start(c)
    rwkv_comb<<<dim3(4096), blk, 0, stream>>>(Cbuf, Abuf);
    // 5c. chunk-local scan with outputs -> o f16 (overlay on r+k region)
    rwkv_scan2<<<dim3(4096), dim3(64), 0, stream>>>((const uint4*)d_out, vs, ru,
                                                    Cbuf, oh, T);

    // 6. groupnorm + gate -> yb f16 (overlay on w+v region; Cbuf dead)
    gn_gate<<<dim3(M), blk, 0, stream>>>(oh, gs, gnw, gnb, yb);

    // 7. out = y @ W_o^T -> d_out f32 (E dead)
    gemm16<<<ggrid(1024), blk, 0, stream>>>(yb, 1024, W_oh, 1024, d_out, 1024,
                                            M, 1024, 1024, nullptr, 4, nullptr, T);
}

// Round 9
// 1691.787 us; speedup vs baseline: 5.1364x; 2.3426x over previous
//
#include <hip/hip_runtime.h>
#include <hip/hip_bf16.h>
#include <hip/hip_fp16.h>
#include <cstdint>

// ---------------------------------------------------------------------------
// RWKV6 attention: f16-MFMA GEMMs + chunked scan with cooperative LDS-ring.
//   Round 9: scan blocks = 256 thr (4 waves), wave0 stages packed E-line
//   (768B/step) into a 4-slot LDS ring via reg-staged loads + ds_write;
//   raw s_barrier + manual lgkmcnt(0) (no vmcnt drain); readers use
//   broadcast ds_read_b128. Kills the r8 per-CU memory-queue bottleneck
//   (was: 16 indep waves x 20 outstanding HBM lines).
// ---------------------------------------------------------------------------

typedef _Float16 half8 __attribute__((ext_vector_type(8)));
typedef float f32x4 __attribute__((ext_vector_type(4)));
typedef unsigned short ushort8 __attribute__((ext_vector_type(8)));

#define CL 512  // chunk length (T/4)

__device__ __forceinline__ float hbits2f(unsigned short us) {
    __half h; *reinterpret_cast<unsigned short*>(&h) = us; return __half2float(h);
}
__device__ __forceinline__ unsigned short f2h(float f) {
    __half h = __float2half(f);
    return *reinterpret_cast<unsigned short*>(&h);
}
__device__ __forceinline__ float2 up2(unsigned int u) {
    return make_float2(hbits2f((unsigned short)(u & 0xFFFF)),
                       hbits2f((unsigned short)(u >> 16)));
}

// ---------------- generic f32 -> f16 cast (weights) -------------------------
__global__ void cast16(const float* __restrict__ src, __half* __restrict__ dst, int n4)
{
    const int i = blockIdx.x * blockDim.x + threadIdx.x;
    if (i >= n4) return;
    const float4 f = *(const float4*)(src + (size_t)i * 4);
    ushort4 u;
    u.x = f2h(f.x); u.y = f2h(f.y); u.z = f2h(f.z); u.w = f2h(f.w);
    *(ushort4*)(dst + (size_t)i * 4) = u;
}

// ---------------- token shift (f16 out) -------------------------------------
__global__ void k_xw_h(const float* __restrict__ X, const float* __restrict__ mu,
                       __half* __restrict__ XW, int M, int T)
{
    const size_t i4 = (size_t)blockIdx.x * blockDim.x + threadIdx.x;
    if (i4 >= (size_t)M * 256) return;
    const size_t idx = i4 * 4;
    const int m = (int)(idx >> 10);
    const int d = (int)(idx & 1023);
    const int t = m & (T - 1);
    const float4 xv = *(const float4*)(X + idx);
    const float4 m4 = *(const float4*)(mu + d);
    float4 xp = make_float4(0.f, 0.f, 0.f, 0.f);
    if (t > 0) xp = *(const float4*)(X + idx - 1024);
    ushort4 o;
    o.x = f2h(xv.x + (xp.x - xv.x) * m4.x);
    o.y = f2h(xv.y + (xp.y - xv.y) * m4.y);
    o.z = f2h(xv.z + (xp.z - xv.z) * m4.z);
    o.w = f2h(xv.w + (xp.w - xv.w) * m4.w);
    *(ushort4*)(XW + idx) = o;
}

// ---------------- f16 MFMA GEMM: C[M,N] = A[M,K] @ B[N,K]^T -----------------
// epi: 0 f16 plain, 1 f16 tanh, 2 f16 bias+delta-lerp(X), 3 f16 bias, 4 f32 plain
#define TS 40  // LDS row stride in halfs (padded from 32)

__global__ __launch_bounds__(256) void gemm16(
    const __half* __restrict__ A, int lda,
    const __half* __restrict__ B, int ldb,
    void* __restrict__ Cv, int ldc,
    int M, int N, int K,
    const float* __restrict__ bias, int epi,
    const float* __restrict__ X, int T)
{
    __shared__ __align__(16) _Float16 As[128 * TS];
    __shared__ __align__(16) _Float16 Bs[128 * TS];

    const int tid = threadIdx.x;

    const int nwg = gridDim.x * gridDim.y;
    int p = blockIdx.y * gridDim.x + blockIdx.x;
    if (!(nwg & 7)) p = (p & 7) * (nwg >> 3) + (p >> 3);
    const int bx = p % gridDim.x, by = p / gridDim.x;

    const int m0 = by * 128;
    const int n0 = bx * 128;
    const int wave = tid >> 6, lane = tid & 63;
    const int wm = wave >> 1, wn = wave & 1;
    const int lr = lane & 15, lk = lane >> 4;

    const int srow = tid >> 1;          // 0..127
    const int sseg = (tid & 1) * 16;    // 0 or 16 halfs

    f32x4 acc[4][4] = {};

    for (int k0 = 0; k0 < K; k0 += 32) {
        const __half* ap = A + (size_t)(m0 + srow) * lda + k0 + sseg;
        ushort8 a0 = *(const ushort8*)ap;
        ushort8 a1 = *(const ushort8*)(ap + 8);
        ushort8 b0 = {0,0,0,0,0,0,0,0}, b1 = {0,0,0,0,0,0,0,0};
        if (n0 + srow < N) {
            const __half* bp = B + (size_t)(n0 + srow) * ldb + k0 + sseg;
            b0 = *(const ushort8*)bp;
            b1 = *(const ushort8*)(bp + 8);
        }
        __syncthreads();
        *(ushort8*)&As[srow * TS + sseg + 0] = a0;
        *(ushort8*)&As[srow * TS + sseg + 8] = a1;
        *(ushort8*)&Bs[srow * TS + sseg + 0] = b0;
        *(ushort8*)&Bs[srow * TS + sseg + 8] = b1;
        __syncthreads();

        half8 af[4], bf[4];
#pragma unroll
        for (int f = 0; f < 4; f++) {
            af[f] = *(const half8*)&As[(wm * 64 + f * 16 + lr) * TS + lk * 8];
            bf[f] = *(const half8*)&Bs[(wn * 64 + f * 16 + lr) * TS + lk * 8];
        }
#pragma unroll
        for (int fm = 0; fm < 4; fm++)
#pragma unroll
            for (int fn = 0; fn < 4; fn++)
                acc[fm][fn] = __builtin_amdgcn_mfma_f32_16x16x32_f16(
                    af[fm], bf[fn], acc[fm][fn], 0, 0, 0);
    }

#pragma unroll
    for (int fm = 0; fm < 4; fm++) {
#pragma unroll
        for (int fn = 0; fn < 4; fn++) {
#pragma unroll
            for (int j = 0; j < 4; j++) {
                const int gm = m0 + wm * 64 + fm * 16 + lk * 4 + j;
                const int gn = n0 + wn * 64 + fn * 16 + lr;
                if (gn >= N) continue;
                float a = acc[fm][fn][j];
                if (epi == 1) {
                    a = tanhf(a);
                    ((__half*)Cv)[(size_t)gm * ldc + gn] = __float2half(a);
                } else if (epi == 2) {
                    a += bias[gn];
                    const float xv = X[(size_t)gm * 1024 + gn];
                    float xp = 0.f;
                    if (gm & (T - 1)) xp = X[(size_t)(gm - 1) * 1024 + gn];
                    ((__half*)Cv)[(size_t)gm * ldc + gn] =
                        __float2half(xv + (xp - xv) * a);
                } else if (epi == 3) {
                    a += bias[gn];
                    ((__half*)Cv)[(size_t)gm * ldc + gn] = __float2half(a);
                } else if (epi == 4) {
                    ((float*)Cv)[(size_t)gm * ldc + gn] = a;
                } else {
                    ((__half*)Cv)[(size_t)gm * ldc + gn] = __float2half(a);
                }
            }
        }
    }
}

// ---------------- prepass: pack E-line + ru ---------------------------------
// E layout per (bh,t): 192 uints (768B):
//   words [0..128)  : rk[k] = r(k) f16 | k(k) f16 << 16
//   words [128..192): dec f16 pairs (dec(2i) | dec(2i+1)<<16)
__global__ __launch_bounds__(256) void k_prep(
    const __half* __restrict__ R, const __half* __restrict__ Kk,
    const __half* __restrict__ W, const float* __restrict__ bonus,
    unsigned* __restrict__ Eu, float* __restrict__ RU, int T)
{
    const int tok = blockIdx.x;
    const int b = tok >> 11, t = tok & 2047;
    const int h = threadIdx.x >> 6, lane = threadIdx.x & 63;
    const size_t base = (size_t)tok * 512 + h * 128 + 2 * lane;
    const unsigned rr = *(const unsigned*)(R + base);   // r(2l), r(2l+1)
    const unsigned kk = *(const unsigned*)(Kk + base);
    const unsigned ww = *(const unsigned*)(W + base);
    const float2 rf = up2(rr), kf = up2(kk), wf = up2(ww);
    const float d0 = __expf(-__expf(wf.x));
    const float d1 = __expf(-__expf(wf.y));
    const float2 uf = *(const float2*)(bonus + h * 128 + 2 * lane);
    float ru = rf.x * uf.x * kf.x + rf.y * uf.y * kf.y;
#pragma unroll
    for (int off = 1; off < 64; off <<= 1) ru += __shfl_xor(ru, off);
    const int bh = b * 4 + h;
    unsigned* ep = Eu + (size_t)(bh * T + t) * 192;
    uint2 rkw;
    rkw.x = (rr & 0xFFFFu) | (kk << 16);           // r(2l)|k(2l)
    rkw.y = (rr >> 16) | (kk & 0xFFFF0000u);       // r(2l+1)|k(2l+1)
    *(uint2*)(ep + 2 * lane) = rkw;
    ep[128 + lane] = (unsigned)f2h(d0) | ((unsigned)f2h(d1) << 16);
    if (lane == 0) RU[(size_t)bh * T + t] = ru;
}

// ---------------- cooperative chunked scan ----------------------------------
// Block = (bh, c, vq): 256 thr = 4 waves; thread (v = tid&63, kh = tid>>6).
// col = vq*64+v; k range = kh*32..+32; S[32]/thread.
// Wave0 stages E-line(768B)+V-slice(128B)+ru per step into a 4-slot LDS ring
// (reg-staged, 4 named bufs = 3-iter latency cover). Raw s_barrier +
// lgkmcnt(0) per step; NO __syncthreads (would drain vmcnt and kill the
// pipeline). PART: accumulates S,A summary (no output); else full scan.
template<bool PART>
__global__ __launch_bounds__(256) void rwkv_coop(
    const uint4* __restrict__ E, const __half* __restrict__ V,
    const float* __restrict__ RU, const float* __restrict__ Cin,
    float* __restrict__ Cout, float* __restrict__ Abuf,
    __half* __restrict__ O, int T)
{
    __shared__ uint4 sE[4][48];
    __shared__ uint4 sV[4][8];
    __shared__ float sRU[4];
    __shared__ float opart[2][4][64];

    const int p = blockIdx.x;
    int bh, c, vq;
    if (PART) {
        const int l = (p & 7) * 48 + (p >> 3);        // 384 blocks, bijective
        bh = l / 12; const int rem = l - bh * 12; c = rem >> 2; vq = rem & 3;
    } else {
        const int l = (p & 7) * 64 + (p >> 3);        // 512 blocks, bijective
        bh = l >> 4; c = (l >> 2) & 3; vq = l & 3;
    }
    const int b = bh >> 2, h = bh & 3;
    const int tid = threadIdx.x;
    const int v = tid & 63, kh = tid >> 6;
    const int t0 = c * CL;
    const int col = vq * 64 + v;

    const uint4* Eg = E + (size_t)(bh * T + t0) * 48;
    const uint4* Vgp = (const uint4*)(V + ((size_t)b * T + t0) * 1024 + h * 256 + vq * 64);
    const float* RUp = RU + (size_t)bh * T + t0;
    __half* Op = O + ((size_t)b * T + t0) * 1024 + h * 256 + col;

    float S[32];
    float A[32];
    if (!PART && c) {
        const float* Sp = Cin + ((size_t)(c - 1) * 32 + bh) * 32768 + col;
#pragma unroll
        for (int j = 0; j < 32; j++) S[j] = Sp[(size_t)(kh * 32 + j) * 256];
    } else {
#pragma unroll
        for (int j = 0; j < 32; j++) S[j] = 0.f;
    }
#pragma unroll
    for (int j = 0; j < 32; j++) A[j] = 1.f;

#define ISSUE(BE, BV, BR, TT)                                                 \
    if (kh == 0 && (TT) < CL) {                                               \
        if (v < 48)      BE = Eg[(size_t)(TT) * 48 + v];                      \
        else if (v < 56) BV = Vgp[(size_t)(TT) * 128 + (v - 48)];             \
        if (v == 56)     BR = RUp[TT];                                        \
    }

#define STAGE(BE, BV, BR, SLOT)                                               \
    if (kh == 0) {                                                            \
        if (v < 48)      sE[SLOT][v] = BE;                                    \
        else if (v < 56) sV[SLOT][v - 48] = BV;                               \
        if (v == 56)     sRU[SLOT] = BR;                                      \
    }

#define BAR() do {                                                            \
        asm volatile("s_waitcnt lgkmcnt(0)" ::: "memory");                    \
        __builtin_amdgcn_s_barrier();                                         \
        __builtin_amdgcn_sched_barrier(0);                                    \
    } while (0)

#define COMPUTE(SLOT, TT)                                                     \
    {                                                                         \
        uint4 rq[8], dq[4];                                                   \
        _Pragma("unroll") for (int i = 0; i < 8; i++)                         \
            rq[i] = sE[SLOT][kh * 8 + i];                                     \
        _Pragma("unroll") for (int i = 0; i < 4; i++)                         \
            dq[i] = sE[SLOT][32 + kh * 4 + i];                                \
        const float vv = __half2float(((const __half*)&sV[SLOT][0])[v]);      \
        const unsigned* rw = (const unsigned*)rq;                             \
        const unsigned* dwp = (const unsigned*)dq;                            \
        float osum = 0.f;                                                     \
        _Pragma("unroll") for (int j2 = 0; j2 < 16; j2++) {                   \
            const float2 rk0 = up2(rw[2 * j2]);                               \
            const float2 rk1 = up2(rw[2 * j2 + 1]);                           \
            const float2 dd = up2(dwp[j2]);                                   \
            osum = fmaf(rk0.x, S[2 * j2], osum);                              \
            S[2 * j2] = fmaf(dd.x, S[2 * j2], rk0.y * vv);                    \
            osum = fmaf(rk1.x, S[2 * j2 + 1], osum);                          \
            S[2 * j2 + 1] = fmaf(dd.y, S[2 * j2 + 1], rk1.y * vv);            \
            if (PART) { A[2 * j2] *= dd.x; A[2 * j2 + 1] *= dd.y; }           \
        }                                                                     \
        if (!PART) {                                                          \
            if (kh == 0) osum = fmaf(sRU[SLOT], vv, osum);                    \
            opart[(TT) & 1][kh][v] = osum;                                    \
            if (kh == 3 && (TT) > 0) {                                        \
                const int pt = (TT) - 1;                                      \
                const float oo = opart[pt & 1][0][v] + opart[pt & 1][1][v]    \
                               + opart[pt & 1][2][v] + opart[pt & 1][3][v];   \
                Op[(size_t)pt * 1024] = __float2half(oo);                     \
            }                                                                 \
        }                                                                     \
    }

    uint4 e0 = {}, e1 = {}, e2 = {}, e3 = {};
    uint4 v0 = {}, v1 = {}, v2 = {}, v3 = {};
    float r0 = 0.f, r1 = 0.f, r2 = 0.f, r3 = 0.f;

    ISSUE(e0, v0, r0, 0)
    ISSUE(e1, v1, r1, 1)
    ISSUE(e2, v2, r2, 2)
    ISSUE(e3, v3, r3, 3)
    STAGE(e0, v0, r0, 0)
    BAR();

    for (int t = 0; t < CL; t += 4) {
        STAGE(e1, v1, r1, 1)
        ISSUE(e0, v0, r0, t + 4)
        COMPUTE(0, t)
        BAR();
        STAGE(e2, v2, r2, 2)
        ISSUE(e1, v1, r1, t + 5)
        COMPUTE(1, t + 1)
        BAR();
        STAGE(e3, v3, r3, 3)
        ISSUE(e2, v2, r2, t + 6)
        COMPUTE(2, t + 2)
        BAR();
        if (t + 4 < CL) STAGE(e0, v0, r0, 0)
        ISSUE(e3, v3, r3, t + 7)
        COMPUTE(3, t + 3)
        BAR();
    }

    if (!PART && kh == 3) {
        const int pt = CL - 1;
        const float oo = opart[pt & 1][0][v] + opart[pt & 1][1][v]
                       + opart[pt & 1][2][v] + opart[pt & 1][3][v];
        Op[(size_t)pt * 1024] = __float2half(oo);
    }
    if (PART) {
        float* Cw = Cout + ((size_t)c * 32 + bh) * 32768 + col;
#pragma unroll
        for (int j = 0; j < 32; j++) Cw[(size_t)(kh * 32 + j) * 256] = S[j];
        if (v == 0) {
            float* Aw = Abuf + ((size_t)c * 32 + bh) * 128 + kh * 32;
#pragma unroll
            for (int j = 0; j < 32; j++) Aw[j] = A[j];
        }
    }
#undef ISSUE
#undef STAGE
#undef BAR
#undef COMPUTE
}

// ---------------- combine: C[c-1] := S_start(c) -----------------------------
__global__ __launch_bounds__(256) void rwkv_comb(
    float* __restrict__ C, const float* __restrict__ A)
{
    const int gid = blockIdx.x * 256 + threadIdx.x;   // 1M threads
    const int bh = gid >> 15;
    const int elem = gid & 32767;
    const int k = elem >> 8;
    float s = C[(size_t)bh * 32768 + elem];                       // B_0
    s = A[(size_t)(32 + bh) * 128 + k] * s +
        C[((size_t)32 + bh) * 32768 + elem];
    C[((size_t)32 + bh) * 32768 + elem] = s;                      // S_start(2)
    s = A[(size_t)(64 + bh) * 128 + k] * s +
        C[((size_t)64 + bh) * 32768 + elem];
    C[((size_t)64 + bh) * 32768 + elem] = s;                      // S_start(3)
}

// ---------------- groupnorm + silu gate (f16 in/out) ------------------------
__global__ __launch_bounds__(256) void gn_gate(
    const __half* __restrict__ Obuf, const __half* __restrict__ G,
    const float* __restrict__ gnw, const float* __restrict__ gnb,
    __half* __restrict__ Y)
{
    const int token = blockIdx.x;
    const int wave = threadIdx.x >> 6, lane = threadIdx.x & 63;
    const size_t base = (size_t)token * 1024 + wave * 256 + lane * 4;
    const ushort4 xu = *(const ushort4*)(Obuf + base);
    const float x0 = hbits2f(xu.x), x1 = hbits2f(xu.y),
                x2 = hbits2f(xu.z), x3 = hbits2f(xu.w);
    float sum = x0 + x1 + x2 + x3;
    float ssq = x0 * x0 + x1 * x1 + x2 * x2 + x3 * x3;
#pragma unroll
    for (int off = 32; off >= 1; off >>= 1) {
        sum += __shfl_xor(sum, off);
        ssq += __shfl_xor(ssq, off);
    }
    const float mean = sum * (1.f / 256.f);
    const float var = ssq * (1.f / 256.f) - mean * mean;
    const float rstd = rsqrtf(var + 1e-5f);
    const int c0 = wave * 256 + lane * 4;
    const float4 w4 = *(const float4*)(gnw + c0);
    const float4 b4 = *(const float4*)(gnb + c0);
    const ushort4 gu = *(const ushort4*)(G + base);
    const float g0 = hbits2f(gu.x), g1 = hbits2f(gu.y),
                g2 = hbits2f(gu.z), g3 = hbits2f(gu.w);
    ushort4 y;
    y.x = f2h(((x0 - mean) * rstd * w4.x + b4.x) * (g0 / (1.f + __expf(-g0))));
    y.y = f2h(((x1 - mean) * rstd * w4.y + b4.y) * (g1 / (1.f + __expf(-g1))));
    y.z = f2h(((x2 - mean) * rstd * w4.z + b4.z) * (g2 / (1.f + __expf(-g2))));
    y.w = f2h(((x3 - mean) * rstd * w4.w + b4.w) * (g3 / (1.f + __expf(-g3))));
    *(ushort4*)(Y + base) = y;
}

// ---------------------------------------------------------------------------
extern "C" void kernel_launch(void* const* d_in, const int* in_sizes, int n_in,
                              void* d_out, int out_size, void* d_ws, size_t ws_size,
                              hipStream_t stream)
{
    (void)in_sizes; (void)n_in; (void)out_size; (void)ws_size;
    const float* x      = (const float*)d_in[0];
    const float* mu_x   = (const float*)d_in[1];
    const float* W_x1   = (const float*)d_in[2];
    const float* W_x2   = (const float*)d_in[3];
    const float* x_bias = (const float*)d_in[4];
    const float* W_r    = (const float*)d_in[5];
    const float* W_k    = (const float*)d_in[6];
    const float* W_v    = (const float*)d_in[7];
    const float* W_g    = (const float*)d_in[8];
    const float* A_w    = (const float*)d_in[9];
    const float* B_w    = (const float*)d_in[10];
    const float* b_w    = (const float*)d_in[11];
    const float* bonus  = (const float*)d_in[12];
    const float* gnw    = (const float*)d_in[13];
    const float* gnb    = (const float*)d_in[14];
    const float* W_o    = (const float*)d_in[15];

    const int B = 8, T = 2048, M = B * T;

    // d_out: [xw_h | inb_h] f16 -> E (48MiB packed scan lines) -> final f32
    __half* xwh  = (__half*)d_out;
    __half* inbh = xwh + (size_t)M * 1024;

    // ws layout (identical to round-8, proven to fit)
    __half* z   = (__half*)d_ws;                    // M*160
    __half* w1  = z   + (size_t)M * 160;            // M*64
    __half* rs  = w1  + (size_t)M * 64;             // M*512
    __half* ks  = rs  + (size_t)M * 512;            // M*512
    __half* wsm = ks  + (size_t)M * 512;            // M*512 (w stream)
    __half* vs  = wsm + (size_t)M * 512;            // M*1024
    __half* gs  = vs  + (size_t)M * 1024;           // M*1024
    float*  ru  = (float*)(gs + (size_t)M * 1024);  // 32*T f32
    __half* wgt = (__half*)(ru + (size_t)32 * T);   // f16 weights
    __half* oh  = rs;                               // overlay: o f16 (r dead post-prep)
    __half* yb  = wsm;                              // overlay: y f16 (post-scan)
    float*  Cbuf = (float*)wsm;                     // overlay: 3*32*32768 f32
    float*  Abuf = (float*)z;                       // overlay: 3*32*128 f32

    __half* W_x1h = wgt;                 // 160*1024
    __half* W_x2h = W_x1h + 163840;      // 1024*160
    __half* W_rh  = W_x2h + 163840;      // 512*1024
    __half* W_kh  = W_rh + 524288;
    __half* W_vh  = W_kh + 524288;       // 1024*1024
    __half* W_gh  = W_vh + 1048576;
    __half* A_wh  = W_gh + 1048576;      // 64*1024
    __half* B_wh  = A_wh + 65536;        // 512*64
    __half* W_oh  = B_wh + 32768;        // 1024*1024

    const dim3 blk(256);
    auto cgrid = [](int n) { return dim3((n / 4 + 255) / 256); };
    cast16<<<cgrid(163840), blk, 0, stream>>>(W_x1, W_x1h, 163840 / 4);
    cast16<<<cgrid(163840), blk, 0, stream>>>(W_x2, W_x2h, 163840 / 4);
    cast16<<<cgrid(524288), blk, 0, stream>>>(W_r, W_rh, 524288 / 4);
    cast16<<<cgrid(524288), blk, 0, stream>>>(W_k, W_kh, 524288 / 4);
    cast16<<<cgrid(1048576), blk, 0, stream>>>(W_v, W_vh, 1048576 / 4);
    cast16<<<cgrid(1048576), blk, 0, stream>>>(W_g, W_gh, 1048576 / 4);
    cast16<<<cgrid(65536), blk, 0, stream>>>(A_w, A_wh, 65536 / 4);
    cast16<<<cgrid(32768), blk, 0, stream>>>(B_w, B_wh, 32768 / 4);
    cast16<<<cgrid(1048576), blk, 0, stream>>>(W_o, W_oh, 1048576 / 4);

    // 1. xw = lerp(x, mu_x) -> f16
    k_xw_h<<<(M * 256 + 255) / 256, blk, 0, stream>>>(x, mu_x, xwh, M, T);

    auto ggrid = [&](int N) { return dim3((N + 127) / 128, M / 128); };

    // 2. z = tanh(xw @ W_x1^T)
    gemm16<<<ggrid(160), blk, 0, stream>>>(xwh, 1024, W_x1h, 1024, z, 160,
                                           M, 160, 1024, nullptr, 1, nullptr, T);

    // 3. branches
    for (int n = 0; n < 5; ++n) {
        gemm16<<<ggrid(1024), blk, 0, stream>>>(z + n * 32, 160, W_x2h + n * 32, 160,
                                                inbh, 1024, M, 1024, 32,
                                                x_bias + n * 1024, 2, x, T);
        if (n == 1) {
            gemm16<<<ggrid(64), blk, 0, stream>>>(inbh, 1024, A_wh, 1024, w1, 64,
                                                  M, 64, 1024, nullptr, 1, nullptr, T);
            gemm16<<<ggrid(512), blk, 0, stream>>>(w1, 64, B_wh, 64, wsm, 512,
                                                   M, 512, 64, b_w, 3, nullptr, T);
        } else {
            __half* Cp = (n == 0) ? rs : (n == 2) ? ks : (n == 3) ? vs : gs;
            const __half* Wp = (n == 0) ? W_rh : (n == 2) ? W_kh : (n == 3) ? W_vh : W_gh;
            const int N = (n == 0 || n == 2) ? 512 : 1024;
            gemm16<<<ggrid(N), blk, 0, stream>>>(inbh, 1024, Wp, 1024, Cp, N,
                                                 M, N, 1024, nullptr, 0, nullptr, T);
        }
    }

    // 4. prepass -> packed E lines (d_out; xwh/inbh dead), ru
    k_prep<<<dim3(M), blk, 0, stream>>>(rs, ks, wsm, bonus,
                                        (unsigned*)d_out, ru, T);

    // 5a. chunk summaries (c=0..2) -> Cbuf, Abuf
    rwkv_coop<true><<<dim3(384), blk, 0, stream>>>(
        (const uint4*)d_out, vs, ru, Cbuf, Cbuf, Abuf, oh, T);
    // 5b. combine
    rwkv_comb<<<dim3(4096), blk, 0, stream>>>(Cbuf, Abuf);
    // 5c. chunk-local scan with outputs -> o f16
    rwkv_coop<false><<<dim3(512), blk, 0, stream>>>(
        (const uint4*)d_out, vs, ru, Cbuf, Cbuf, Abuf, oh, T);

    // 6. groupnorm + gate -> yb
    gn_gate<<<dim3(M), blk, 0, stream>>>(oh, gs, gnw, gnb, yb);

    // 7. out = y @ W_o^T -> d_out f32 (E dead)
    gemm16<<<ggrid(1024), blk, 0, stream>>>(yb, 1024, W_oh, 1024, d_out, 1024,
                                            M, 1024, 1024, nullptr, 4, nullptr, T);
}

// Round 10
// 1222.356 us; speedup vs baseline: 7.1090x; 1.3840x over previous
//
#include <hip/hip_runtime.h>
#include <hip/hip_bf16.h>
#include <hip/hip_fp16.h>
#include <cstdint>

// ---------------------------------------------------------------------------
// RWKV6 attention: f16-MFMA GEMMs + chunked scan with cooperative LDS-ring.
//   Round 10: scan repartition (8k x 4v per thread) -> 4 ds_reads/step
//   (was 12) + 3x less unpack; shfl-xor kg-reduction (opart gone); 2 steps
//   per barrier (waves 0/1 co-stage); rk XOR bank-swizzle.
// ---------------------------------------------------------------------------

typedef _Float16 half8 __attribute__((ext_vector_type(8)));
typedef float f32x4 __attribute__((ext_vector_type(4)));
typedef unsigned short ushort8 __attribute__((ext_vector_type(8)));

#define CL 512          // chunk length (T/4)
#define NP (CL / 2)     // pair-steps per chunk

__device__ __forceinline__ float hbits2f(unsigned short us) {
    __half h; *reinterpret_cast<unsigned short*>(&h) = us; return __half2float(h);
}
__device__ __forceinline__ unsigned short f2h(float f) {
    __half h = __float2half(f);
    return *reinterpret_cast<unsigned short*>(&h);
}
__device__ __forceinline__ float2 up2(unsigned int u) {
    return make_float2(hbits2f((unsigned short)(u & 0xFFFF)),
                       hbits2f((unsigned short)(u >> 16)));
}

// ---------------- generic f32 -> f16 cast (weights) -------------------------
__global__ void cast16(const float* __restrict__ src, __half* __restrict__ dst, int n4)
{
    const int i = blockIdx.x * blockDim.x + threadIdx.x;
    if (i >= n4) return;
    const float4 f = *(const float4*)(src + (size_t)i * 4);
    ushort4 u;
    u.x = f2h(f.x); u.y = f2h(f.y); u.z = f2h(f.z); u.w = f2h(f.w);
    *(ushort4*)(dst + (size_t)i * 4) = u;
}

// ---------------- token shift (f16 out) -------------------------------------
__global__ void k_xw_h(const float* __restrict__ X, const float* __restrict__ mu,
                       __half* __restrict__ XW, int M, int T)
{
    const size_t i4 = (size_t)blockIdx.x * blockDim.x + threadIdx.x;
    if (i4 >= (size_t)M * 256) return;
    const size_t idx = i4 * 4;
    const int m = (int)(idx >> 10);
    const int d = (int)(idx & 1023);
    const int t = m & (T - 1);
    const float4 xv = *(const float4*)(X + idx);
    const float4 m4 = *(const float4*)(mu + d);
    float4 xp = make_float4(0.f, 0.f, 0.f, 0.f);
    if (t > 0) xp = *(const float4*)(X + idx - 1024);
    ushort4 o;
    o.x = f2h(xv.x + (xp.x - xv.x) * m4.x);
    o.y = f2h(xv.y + (xp.y - xv.y) * m4.y);
    o.z = f2h(xv.z + (xp.z - xv.z) * m4.z);
    o.w = f2h(xv.w + (xp.w - xv.w) * m4.w);
    *(ushort4*)(XW + idx) = o;
}

// ---------------- f16 MFMA GEMM: C[M,N] = A[M,K] @ B[N,K]^T -----------------
// epi: 0 f16 plain, 1 f16 tanh, 2 f16 bias+delta-lerp(X), 3 f16 bias, 4 f32 plain
#define TS 40  // LDS row stride in halfs (padded from 32)

__global__ __launch_bounds__(256) void gemm16(
    const __half* __restrict__ A, int lda,
    const __half* __restrict__ B, int ldb,
    void* __restrict__ Cv, int ldc,
    int M, int N, int K,
    const float* __restrict__ bias, int epi,
    const float* __restrict__ X, int T)
{
    __shared__ __align__(16) _Float16 As[128 * TS];
    __shared__ __align__(16) _Float16 Bs[128 * TS];

    const int tid = threadIdx.x;

    const int nwg = gridDim.x * gridDim.y;
    int p = blockIdx.y * gridDim.x + blockIdx.x;
    if (!(nwg & 7)) p = (p & 7) * (nwg >> 3) + (p >> 3);
    const int bx = p % gridDim.x, by = p / gridDim.x;

    const int m0 = by * 128;
    const int n0 = bx * 128;
    const int wave = tid >> 6, lane = tid & 63;
    const int wm = wave >> 1, wn = wave & 1;
    const int lr = lane & 15, lk = lane >> 4;

    const int srow = tid >> 1;          // 0..127
    const int sseg = (tid & 1) * 16;    // 0 or 16 halfs

    f32x4 acc[4][4] = {};

    for (int k0 = 0; k0 < K; k0 += 32) {
        const __half* ap = A + (size_t)(m0 + srow) * lda + k0 + sseg;
        ushort8 a0 = *(const ushort8*)ap;
        ushort8 a1 = *(const ushort8*)(ap + 8);
        ushort8 b0 = {0,0,0,0,0,0,0,0}, b1 = {0,0,0,0,0,0,0,0};
        if (n0 + srow < N) {
            const __half* bp = B + (size_t)(n0 + srow) * ldb + k0 + sseg;
            b0 = *(const ushort8*)bp;
            b1 = *(const ushort8*)(bp + 8);
        }
        __syncthreads();
        *(ushort8*)&As[srow * TS + sseg + 0] = a0;
        *(ushort8*)&As[srow * TS + sseg + 8] = a1;
        *(ushort8*)&Bs[srow * TS + sseg + 0] = b0;
        *(ushort8*)&Bs[srow * TS + sseg + 8] = b1;
        __syncthreads();

        half8 af[4], bf[4];
#pragma unroll
        for (int f = 0; f < 4; f++) {
            af[f] = *(const half8*)&As[(wm * 64 + f * 16 + lr) * TS + lk * 8];
            bf[f] = *(const half8*)&Bs[(wn * 64 + f * 16 + lr) * TS + lk * 8];
        }
#pragma unroll
        for (int fm = 0; fm < 4; fm++)
#pragma unroll
            for (int fn = 0; fn < 4; fn++)
                acc[fm][fn] = __builtin_amdgcn_mfma_f32_16x16x32_f16(
                    af[fm], bf[fn], acc[fm][fn], 0, 0, 0);
    }

#pragma unroll
    for (int fm = 0; fm < 4; fm++) {
#pragma unroll
        for (int fn = 0; fn < 4; fn++) {
#pragma unroll
            for (int j = 0; j < 4; j++) {
                const int gm = m0 + wm * 64 + fm * 16 + lk * 4 + j;
                const int gn = n0 + wn * 64 + fn * 16 + lr;
                if (gn >= N) continue;
                float a = acc[fm][fn][j];
                if (epi == 1) {
                    a = tanhf(a);
                    ((__half*)Cv)[(size_t)gm * ldc + gn] = __float2half(a);
                } else if (epi == 2) {
                    a += bias[gn];
                    const float xv = X[(size_t)gm * 1024 + gn];
                    float xp = 0.f;
                    if (gm & (T - 1)) xp = X[(size_t)(gm - 1) * 1024 + gn];
                    ((__half*)Cv)[(size_t)gm * ldc + gn] =
                        __float2half(xv + (xp - xv) * a);
                } else if (epi == 3) {
                    a += bias[gn];
                    ((__half*)Cv)[(size_t)gm * ldc + gn] = __float2half(a);
                } else if (epi == 4) {
                    ((float*)Cv)[(size_t)gm * ldc + gn] = a;
                } else {
                    ((__half*)Cv)[(size_t)gm * ldc + gn] = __float2half(a);
                }
            }
        }
    }
}

// ---------------- prepass: pack E-line + ru ---------------------------------
// E layout per (bh,t): 192 uints (768B):
//   words [0..128)  : rk[k] = r(k) f16 | k(k) f16 << 16
//   words [128..192): dec f16 pairs (dec(2i) | dec(2i+1)<<16)
__global__ __launch_bounds__(256) void k_prep(
    const __half* __restrict__ R, const __half* __restrict__ Kk,
    const __half* __restrict__ W, const float* __restrict__ bonus,
    unsigned* __restrict__ Eu, float* __restrict__ RU, int T)
{
    const int tok = blockIdx.x;
    const int b = tok >> 11, t = tok & 2047;
    const int h = threadIdx.x >> 6, lane = threadIdx.x & 63;
    const size_t base = (size_t)tok * 512 + h * 128 + 2 * lane;
    const unsigned rr = *(const unsigned*)(R + base);   // r(2l), r(2l+1)
    const unsigned kk = *(const unsigned*)(Kk + base);
    const unsigned ww = *(const unsigned*)(W + base);
    const float2 rf = up2(rr), kf = up2(kk), wf = up2(ww);
    const float d0 = __expf(-__expf(wf.x));
    const float d1 = __expf(-__expf(wf.y));
    const float2 uf = *(const float2*)(bonus + h * 128 + 2 * lane);
    float ru = rf.x * uf.x * kf.x + rf.y * uf.y * kf.y;
#pragma unroll
    for (int off = 1; off < 64; off <<= 1) ru += __shfl_xor(ru, off);
    const int bh = b * 4 + h;
    unsigned* ep = Eu + (size_t)(bh * T + t) * 192;
    uint2 rkw;
    rkw.x = (rr & 0xFFFFu) | (kk << 16);           // r(2l)|k(2l)
    rkw.y = (rr >> 16) | (kk & 0xFFFF0000u);       // r(2l+1)|k(2l+1)
    *(uint2*)(ep + 2 * lane) = rkw;
    ep[128 + lane] = (unsigned)f2h(d0) | ((unsigned)f2h(d1) << 16);
    if (lane == 0) RU[(size_t)bh * T + t] = ru;
}

// ---------------- cooperative chunked scan (paired steps) -------------------
// Block = (bh, c, vq): 256 thr. Thread: kg = tid&15 (8 k-slots), vg = tid>>4
// (4 v-cols). S[32] = S[kk*4+vi]. Waves 0,1 stage steps 2p,2p+1 of each pair
// into a 4-slot LDS ring; raw s_barrier + lgkmcnt(0) per pair. rk uint4s
// stored XOR-swizzled (i^(i>>3)) -> 2-way banks on kg-strided reads.
// osum reduced across kg lanes via shfl_xor; kg==0 writes 4 cols (ushort4).
template<bool PART>
__global__ __launch_bounds__(256) void rwkv_coop(
    const uint4* __restrict__ E, const __half* __restrict__ V,
    const float* __restrict__ RU, const float* __restrict__ Cin,
    float* __restrict__ Cout, float* __restrict__ Abuf,
    __half* __restrict__ O, int T)
{
    __shared__ uint4 sE[4][96];
    __shared__ uint4 sV[4][16];
    __shared__ float sRU[4][2];

    const int p = blockIdx.x;
    int bh, c, vq;
    if (PART) {
        const int l = (p & 7) * 48 + (p >> 3);        // 384 blocks, bijective
        bh = l / 12; const int rem = l - bh * 12; c = rem >> 2; vq = rem & 3;
    } else {
        const int l = (p & 7) * 64 + (p >> 3);        // 512 blocks, bijective
        bh = l >> 4; c = (l >> 2) & 3; vq = l & 3;
    }
    const int b = bh >> 2, h = bh & 3;
    const int tid = threadIdx.x;
    const int w = tid >> 6, lane = tid & 63;
    const int kg = tid & 15, vg = tid >> 4;
    const int t0 = c * CL;

    const uint4* Eg = E + (size_t)(bh * T + t0) * 48;
    const uint4* Vgp = (const uint4*)(V + ((size_t)b * T + t0) * 1024 + h * 256 + vq * 64);
    const float* RUp = RU + (size_t)bh * T + t0;
    __half* Op = O + ((size_t)b * T + t0) * 1024 + h * 256 + vq * 64 + vg * 4;

    float S[32];
    float Aacc[8];
    if (!PART && c) {
        const float* Sp = Cin + ((size_t)(c - 1) * 32 + bh) * 32768 + vq * 64 + vg * 4;
#pragma unroll
        for (int kk = 0; kk < 8; kk++) {
            const float4 s4 = *(const float4*)(Sp + (size_t)(kg * 8 + kk) * 256);
            S[kk * 4 + 0] = s4.x; S[kk * 4 + 1] = s4.y;
            S[kk * 4 + 2] = s4.z; S[kk * 4 + 3] = s4.w;
        }
    } else {
#pragma unroll
        for (int j = 0; j < 32; j++) S[j] = 0.f;
    }
#pragma unroll
    for (int j = 0; j < 8; j++) Aacc[j] = 1.f;

    // swizzled rk indices for this kg (compile-time-constant form)
    const int i0 = (kg * 2) ^ ((kg * 2) >> 3);
    const int i1 = (kg * 2 + 1) ^ ((kg * 2 + 1) >> 3);

#define ISSUE(BE, BV, BR, PP)                                                 \
    if (w < 2 && (PP) < NP) {                                                 \
        const int tt = (PP) * 2 + w;                                          \
        if (lane < 48)      BE = Eg[(size_t)tt * 48 + lane];                  \
        else if (lane < 56) BV = Vgp[(size_t)tt * 128 + (lane - 48)];         \
        if (lane == 56)     BR = RUp[tt];                                     \
    }

#define STAGE(BE, BV, BR, SLOT)                                               \
    if (w < 2) {                                                              \
        if (lane < 32)      sE[SLOT][w * 48 + (lane ^ (lane >> 3))] = BE;     \
        else if (lane < 48) sE[SLOT][w * 48 + lane] = BE;                     \
        else if (lane < 56) sV[SLOT][w * 8 + (lane - 48)] = BV;               \
        if (lane == 56)     sRU[SLOT][w] = BR;                                \
    }

#define BAR() do {                                                            \
        asm volatile("s_waitcnt lgkmcnt(0)" ::: "memory");                    \
        __builtin_amdgcn_s_barrier();                                         \
        __builtin_amdgcn_sched_barrier(0);                                    \
    } while (0)

#define COMPUTE(SLOT, SUB, TT)                                                \
    {                                                                         \
        const uint4 rka = sE[SLOT][(SUB) * 48 + i0];                          \
        const uint4 rkb = sE[SLOT][(SUB) * 48 + i1];                          \
        const uint4 dq  = sE[SLOT][(SUB) * 48 + 32 + kg];                     \
        const uint2 vw  = *(const uint2*)((const unsigned*)&sV[SLOT][(SUB) * 8] + vg * 2); \
        const unsigned rw_[8] = {rka.x, rka.y, rka.z, rka.w,                  \
                                 rkb.x, rkb.y, rkb.z, rkb.w};                 \
        const unsigned dw_[4] = {dq.x, dq.y, dq.z, dq.w};                     \
        float r_[8], k_[8], d_[8], vv_[4];                                    \
        _Pragma("unroll") for (int j = 0; j < 8; j++) {                       \
            const float2 rk = up2(rw_[j]); r_[j] = rk.x; k_[j] = rk.y;        \
        }                                                                     \
        _Pragma("unroll") for (int j = 0; j < 4; j++) {                       \
            const float2 dd = up2(dw_[j]); d_[2 * j] = dd.x; d_[2 * j + 1] = dd.y; \
        }                                                                     \
        { const float2 va = up2(vw.x), vb = up2(vw.y);                        \
          vv_[0] = va.x; vv_[1] = va.y; vv_[2] = vb.x; vv_[3] = vb.y; }       \
        float osum[4] = {0.f, 0.f, 0.f, 0.f};                                 \
        _Pragma("unroll") for (int kk = 0; kk < 8; kk++) {                    \
            _Pragma("unroll") for (int vi = 0; vi < 4; vi++) {                \
                osum[vi] = fmaf(r_[kk], S[kk * 4 + vi], osum[vi]);            \
                S[kk * 4 + vi] = fmaf(d_[kk], S[kk * 4 + vi], k_[kk] * vv_[vi]); \
            }                                                                 \
            if (PART) Aacc[kk] *= d_[kk];                                     \
        }                                                                     \
        if (!PART) {                                                          \
            _Pragma("unroll") for (int vi = 0; vi < 4; vi++) {                \
                osum[vi] += __shfl_xor(osum[vi], 1);                          \
                osum[vi] += __shfl_xor(osum[vi], 2);                          \
                osum[vi] += __shfl_xor(osum[vi], 4);                          \
                osum[vi] += __shfl_xor(osum[vi], 8);                          \
            }                                                                 \
            if (kg == 0) {                                                    \
                const float ru_ = sRU[SLOT][SUB];                             \
                ushort4 ou;                                                   \
                ou.x = f2h(osum[0] + ru_ * vv_[0]);                           \
                ou.y = f2h(osum[1] + ru_ * vv_[1]);                           \
                ou.z = f2h(osum[2] + ru_ * vv_[2]);                           \
                ou.w = f2h(osum[3] + ru_ * vv_[3]);                           \
                *(ushort4*)(Op + (size_t)(TT) * 1024) = ou;                   \
            }                                                                 \
        }                                                                     \
    }

#define COMPUTE2(SLOT, PP)  COMPUTE(SLOT, 0, (PP) * 2) COMPUTE(SLOT, 1, (PP) * 2 + 1)

    uint4 e0 = {}, e1 = {}, e2 = {}, e3 = {};
    uint4 v0 = {}, v1 = {}, v2 = {}, v3 = {};
    float r0 = 0.f, r1 = 0.f, r2 = 0.f, r3 = 0.f;

    ISSUE(e0, v0, r0, 0)
    ISSUE(e1, v1, r1, 1)
    ISSUE(e2, v2, r2, 2)
    ISSUE(e3, v3, r3, 3)
    STAGE(e0, v0, r0, 0)
    BAR();

    for (int ps = 0; ps < NP; ps += 4) {
        STAGE(e1, v1, r1, 1)
        ISSUE(e0, v0, r0, ps + 4)
        COMPUTE2(0, ps)
        BAR();
        STAGE(e2, v2, r2, 2)
        ISSUE(e1, v1, r1, ps + 5)
        COMPUTE2(1, ps + 1)
        BAR();
        STAGE(e3, v3, r3, 3)
        ISSUE(e2, v2, r2, ps + 6)
        COMPUTE2(2, ps + 2)
        BAR();
        if (ps + 4 < NP) STAGE(e0, v0, r0, 0)
        ISSUE(e3, v3, r3, ps + 7)
        COMPUTE2(3, ps + 3)
        BAR();
    }

    if (PART) {
        float* Cw = Cout + ((size_t)c * 32 + bh) * 32768 + vq * 64 + vg * 4;
#pragma unroll
        for (int kk = 0; kk < 8; kk++) {
            float4 s4;
            s4.x = S[kk * 4 + 0]; s4.y = S[kk * 4 + 1];
            s4.z = S[kk * 4 + 2]; s4.w = S[kk * 4 + 3];
            *(float4*)(Cw + (size_t)(kg * 8 + kk) * 256) = s4;
        }
        if (vg == 0) {
            float* Aw = Abuf + ((size_t)c * 32 + bh) * 128 + kg * 8;
#pragma unroll
            for (int kk = 0; kk < 8; kk++) Aw[kk] = Aacc[kk];
        }
    }
#undef ISSUE
#undef STAGE
#undef BAR
#undef COMPUTE
#undef COMPUTE2
}

// ---------------- combine: C[c-1] := S_start(c) -----------------------------
__global__ __launch_bounds__(256) void rwkv_comb(
    float* __restrict__ C, const float* __restrict__ A)
{
    const int gid = blockIdx.x * 256 + threadIdx.x;   // 1M threads
    const int bh = gid >> 15;
    const int elem = gid & 32767;
    const int k = elem >> 8;
    float s = C[(size_t)bh * 32768 + elem];                       // B_0
    s = A[(size_t)(32 + bh) * 128 + k] * s +
        C[((size_t)32 + bh) * 32768 + elem];
    C[((size_t)32 + bh) * 32768 + elem] = s;                      // S_start(2)
    s = A[(size_t)(64 + bh) * 128 + k] * s +
        C[((size_t)64 + bh) * 32768 + elem];
    C[((size_t)64 + bh) * 32768 + elem] = s;                      // S_start(3)
}

// ---------------- groupnorm + silu gate (f16 in/out) ------------------------
__global__ __launch_bounds__(256) void gn_gate(
    const __half* __restrict__ Obuf, const __half* __restrict__ G,
    const float* __restrict__ gnw, const float* __restrict__ gnb,
    __half* __restrict__ Y)
{
    const int token = blockIdx.x;
    const int wave = threadIdx.x >> 6, lane = threadIdx.x & 63;
    const size_t base = (size_t)token * 1024 + wave * 256 + lane * 4;
    const ushort4 xu = *(const ushort4*)(Obuf + base);
    const float x0 = hbits2f(xu.x), x1 = hbits2f(xu.y),
                x2 = hbits2f(xu.z), x3 = hbits2f(xu.w);
    float sum = x0 + x1 + x2 + x3;
    float ssq = x0 * x0 + x1 * x1 + x2 * x2 + x3 * x3;
#pragma unroll
    for (int off = 32; off >= 1; off >>= 1) {
        sum += __shfl_xor(sum, off);
        ssq += __shfl_xor(ssq, off);
    }
    const float mean = sum * (1.f / 256.f);
    const float var = ssq * (1.f / 256.f) - mean * mean;
    const float rstd = rsqrtf(var + 1e-5f);
    const int c0 = wave * 256 + lane * 4;
    const float4 w4 = *(const float4*)(gnw + c0);
    const float4 b4 = *(const float4*)(gnb + c0);
    const ushort4 gu = *(const ushort4*)(G + base);
    const float g0 = hbits2f(gu.x), g1 = hbits2f(gu.y),
                g2 = hbits2f(gu.z), g3 = hbits2f(gu.w);
    ushort4 y;
    y.x = f2h(((x0 - mean) * rstd * w4.x + b4.x) * (g0 / (1.f + __expf(-g0))));
    y.y = f2h(((x1 - mean) * rstd * w4.y + b4.y) * (g1 / (1.f + __expf(-g1))));
    y.z = f2h(((x2 - mean) * rstd * w4.z + b4.z) * (g2 / (1.f + __expf(-g2))));
    y.w = f2h(((x3 - mean) * rstd * w4.w + b4.w) * (g3 / (1.f + __expf(-g3))));
    *(ushort4*)(Y + base) = y;
}

// ---------------------------------------------------------------------------
extern "C" void kernel_launch(void* const* d_in, const int* in_sizes, int n_in,
                              void* d_out, int out_size, void* d_ws, size_t ws_size,
                              hipStream_t stream)
{
    (void)in_sizes; (void)n_in; (void)out_size; (void)ws_size;
    const float* x      = (const float*)d_in[0];
    const float* mu_x   = (const float*)d_in[1];
    const float* W_x1   = (const float*)d_in[2];
    const float* W_x2   = (const float*)d_in[3];
    const float* x_bias = (const float*)d_in[4];
    const float* W_r    = (const float*)d_in[5];
    const float* W_k    = (const float*)d_in[6];
    const float* W_v    = (const float*)d_in[7];
    const float* W_g    = (const float*)d_in[8];
    const float* A_w    = (const float*)d_in[9];
    const float* B_w    = (const float*)d_in[10];
    const float* b_w    = (const float*)d_in[11];
    const float* bonus  = (const float*)d_in[12];
    const float* gnw    = (const float*)d_in[13];
    const float* gnb    = (const float*)d_in[14];
    const float* W_o    = (const float*)d_in[15];

    const int B = 8, T = 2048, M = B * T;

    // d_out: [xw_h | inb_h] f16 -> E (48MiB packed scan lines) -> final f32
    __half* xwh  = (__half*)d_out;
    __half* inbh = xwh + (size_t)M * 1024;

    // ws layout (identical to round-8/9, proven to fit)
    __half* z   = (__half*)d_ws;                    // M*160
    __half* w1  = z   + (size_t)M * 160;            // M*64
    __half* rs  = w1  + (size_t)M * 64;             // M*512
    __half* ks  = rs  + (size_t)M * 512;            // M*512
    __half* wsm = ks  + (size_t)M * 512;            // M*512 (w stream)
    __half* vs  = wsm + (size_t)M * 512;            // M*1024
    __half* gs  = vs  + (size_t)M * 1024;           // M*1024
    float*  ru  = (float*)(gs + (size_t)M * 1024);  // 32*T f32
    __half* wgt = (__half*)(ru + (size_t)32 * T);   // f16 weights
    __half* oh  = rs;                               // overlay: o f16
    __half* yb  = wsm;                              // overlay: y f16
    float*  Cbuf = (float*)wsm;                     // overlay: 3*32*32768 f32
    float*  Abuf = (float*)z;                       // overlay: 3*32*128 f32

    __half* W_x1h = wgt;                 // 160*1024
    __half* W_x2h = W_x1h + 163840;      // 1024*160
    __half* W_rh  = W_x2h + 163840;      // 512*1024
    __half* W_kh  = W_rh + 524288;
    __half* W_vh  = W_kh + 524288;       // 1024*1024
    __half* W_gh  = W_vh + 1048576;
    __half* A_wh  = W_gh + 1048576;      // 64*1024
    __half* B_wh  = A_wh + 65536;        // 512*64
    __half* W_oh  = B_wh + 32768;        // 1024*1024

    const dim3 blk(256);
    auto cgrid = [](int n) { return dim3((n / 4 + 255) / 256); };
    cast16<<<cgrid(163840), blk, 0, stream>>>(W_x1, W_x1h, 163840 / 4);
    cast16<<<cgrid(163840), blk, 0, stream>>>(W_x2, W_x2h, 163840 / 4);
    cast16<<<cgrid(524288), blk, 0, stream>>>(W_r, W_rh, 524288 / 4);
    cast16<<<cgrid(524288), blk, 0, stream>>>(W_k, W_kh, 524288 / 4);
    cast16<<<cgrid(1048576), blk, 0, stream>>>(W_v, W_vh, 1048576 / 4);
    cast16<<<cgrid(1048576), blk, 0, stream>>>(W_g, W_gh, 1048576 / 4);
    cast16<<<cgrid(65536), blk, 0, stream>>>(A_w, A_wh, 65536 / 4);
    cast16<<<cgrid(32768), blk, 0, stream>>>(B_w, B_wh, 32768 / 4);
    cast16<<<cgrid(1048576), blk, 0, stream>>>(W_o, W_oh, 1048576 / 4);

    // 1. xw = lerp(x, mu_x) -> f16
    k_xw_h<<<(M * 256 + 255) / 256, blk, 0, stream>>>(x, mu_x, xwh, M, T);

    auto ggrid = [&](int N) { return dim3((N + 127) / 128, M / 128); };

    // 2. z = tanh(xw @ W_x1^T)
    gemm16<<<ggrid(160), blk, 0, stream>>>(xwh, 1024, W_x1h, 1024, z, 160,
                                           M, 160, 1024, nullptr, 1, nullptr, T);

    // 3. branches
    for (int n = 0; n < 5; ++n) {
        gemm16<<<ggrid(1024), blk, 0, stream>>>(z + n * 32, 160, W_x2h + n * 32, 160,
                                                inbh, 1024, M, 1024, 32,
                                                x_bias + n * 1024, 2, x, T);
        if (n == 1) {
            gemm16<<<ggrid(64), blk, 0, stream>>>(inbh, 1024, A_wh, 1024, w1, 64,
                                                  M, 64, 1024, nullptr, 1, nullptr, T);
            gemm16<<<ggrid(512), blk, 0, stream>>>(w1, 64, B_wh, 64, wsm, 512,
                                                   M, 512, 64, b_w, 3, nullptr, T);
        } else {
            __half* Cp = (n == 0) ? rs : (n == 2) ? ks : (n == 3) ? vs : gs;
            const __half* Wp = (n == 0) ? W_rh : (n == 2) ? W_kh : (n == 3) ? W_vh : W_gh;
            const int N = (n == 0 || n == 2) ? 512 : 1024;
            gemm16<<<ggrid(N), blk, 0, stream>>>(inbh, 1024, Wp, 1024, Cp, N,
                                                 M, N, 1024, nullptr, 0, nullptr, T);
        }
    }

    // 4. prepass -> packed E lines (d_out; xwh/inbh dead), ru
    k_prep<<<dim3(M), blk, 0, stream>>>(rs, ks, wsm, bonus,
                                        (unsigned*)d_out, ru, T);

    // 5a. chunk summaries (c=0..2) -> Cbuf, Abuf
    rwkv_coop<true><<<dim3(384), blk, 0, stream>>>(
        (const uint4*)d_out, vs, ru, Cbuf, Cbuf, Abuf, oh, T);
    // 5b. combine
    rwkv_comb<<<dim3(4096), blk, 0, stream>>>(Cbuf, Abuf);
    // 5c. chunk-local scan with outputs -> o f16
    rwkv_coop<false><<<dim3(512), blk, 0, stream>>>(
        (const uint4*)d_out, vs, ru, Cbuf, Cbuf, Abuf, oh, T);

    // 6. groupnorm + gate -> yb
    gn_gate<<<dim3(M), blk, 0, stream>>>(oh, gs, gnw, gnb, yb);

    // 7. out = y @ W_o^T -> d_out f32 (E dead)
    gemm16<<<ggrid(1024), blk, 0, stream>>>(yb, 1024, W_oh, 1024, d_out, 1024,
                                            M, 1024, 1024, nullptr, 4, nullptr, T);
}

// Round 11
// 1204.979 us; speedup vs baseline: 7.2115x; 1.0144x over previous
//
#include <hip/hip_runtime.h>
#include <hip/hip_bf16.h>
#include <hip/hip_fp16.h>
#include <cstdint>

// ---------------------------------------------------------------------------
// RWKV6 attention: f16-MFMA GEMMs + chunked scan with cooperative LDS-ring.
//   Round 11: (a) NC=8 chunks (CL=256) -> scan 1024 blocks (4/CU), part 896;
//   chunk states Cbuf in f16 (14.7MB, fits wsm overlay). (b) gemm16 staging
//   via global_load_lds width=16 into linear [128][32] LDS (m97 pattern),
//   replacing reg-staging (+~1.3x on compute-bound GEMMs).
// ---------------------------------------------------------------------------

typedef _Float16 half8 __attribute__((ext_vector_type(8)));
typedef float f32x4 __attribute__((ext_vector_type(4)));

#define CL 256          // chunk length (T/8)
#define NP (CL / 2)     // pair-steps per chunk
#define NC 8            // chunks

__device__ __forceinline__ float hbits2f(unsigned short us) {
    __half h; *reinterpret_cast<unsigned short*>(&h) = us; return __half2float(h);
}
__device__ __forceinline__ unsigned short f2h(float f) {
    __half h = __float2half(f);
    return *reinterpret_cast<unsigned short*>(&h);
}
__device__ __forceinline__ float2 up2(unsigned int u) {
    return make_float2(hbits2f((unsigned short)(u & 0xFFFF)),
                       hbits2f((unsigned short)(u >> 16)));
}
__device__ __forceinline__ void gload_lds16(const void* g, void* l) {
    __builtin_amdgcn_global_load_lds(
        (const __attribute__((address_space(1))) unsigned*)g,
        (__attribute__((address_space(3))) unsigned*)l, 16, 0, 0);
}

// ---------------- generic f32 -> f16 cast (weights) -------------------------
__global__ void cast16(const float* __restrict__ src, __half* __restrict__ dst, int n4)
{
    const int i = blockIdx.x * blockDim.x + threadIdx.x;
    if (i >= n4) return;
    const float4 f = *(const float4*)(src + (size_t)i * 4);
    ushort4 u;
    u.x = f2h(f.x); u.y = f2h(f.y); u.z = f2h(f.z); u.w = f2h(f.w);
    *(ushort4*)(dst + (size_t)i * 4) = u;
}

// ---------------- token shift (f16 out) -------------------------------------
__global__ void k_xw_h(const float* __restrict__ X, const float* __restrict__ mu,
                       __half* __restrict__ XW, int M, int T)
{
    const size_t i4 = (size_t)blockIdx.x * blockDim.x + threadIdx.x;
    if (i4 >= (size_t)M * 256) return;
    const size_t idx = i4 * 4;
    const int m = (int)(idx >> 10);
    const int d = (int)(idx & 1023);
    const int t = m & (T - 1);
    const float4 xv = *(const float4*)(X + idx);
    const float4 m4 = *(const float4*)(mu + d);
    float4 xp = make_float4(0.f, 0.f, 0.f, 0.f);
    if (t > 0) xp = *(const float4*)(X + idx - 1024);
    ushort4 o;
    o.x = f2h(xv.x + (xp.x - xv.x) * m4.x);
    o.y = f2h(xv.y + (xp.y - xv.y) * m4.y);
    o.z = f2h(xv.z + (xp.z - xv.z) * m4.z);
    o.w = f2h(xv.w + (xp.w - xv.w) * m4.w);
    *(ushort4*)(XW + idx) = o;
}

// ---------------- f16 MFMA GEMM: C[M,N] = A[M,K] @ B[N,K]^T -----------------
// Staging: global_load_lds width=16 into linear [128][32] LDS (m97 pattern).
// epi: 0 f16 plain, 1 f16 tanh, 2 f16 bias+delta-lerp(X), 3 f16 bias, 4 f32 plain
__global__ __launch_bounds__(256) void gemm16(
    const __half* __restrict__ A, int lda,
    const __half* __restrict__ B, int ldb,
    void* __restrict__ Cv, int ldc,
    int M, int N, int K,
    const float* __restrict__ bias, int epi,
    const float* __restrict__ X, int T)
{
    __shared__ __align__(16) _Float16 As[128 * 32];
    __shared__ __align__(16) _Float16 Bs[128 * 32];

    const int tid = threadIdx.x;

    // XCD-aware swizzle: consecutive logical blocks (same A-row panel) on one XCD
    const int nwg = gridDim.x * gridDim.y;
    int p = blockIdx.y * gridDim.x + blockIdx.x;
    if (!(nwg & 7)) p = (p & 7) * (nwg >> 3) + (p >> 3);
    const int bx = p % gridDim.x, by = p / gridDim.x;

    const int m0 = by * 128;
    const int n0 = bx * 128;
    const int wave = tid >> 6, lane = tid & 63;
    const int wm = wave >> 1, wn = wave & 1;
    const int lr = lane & 15, lk = lane >> 4;

    // staging map: thread tid covers LDS bytes tid*16 (half0) and 4096+tid*16
    // (half1); element e = tid*8 -> row = tid>>2, col = (tid&3)*8 halfs.
    const int srow = tid >> 2;          // 0..63
    const int scol = (tid & 3) * 8;     // halfs
    const int arow0 = m0 + srow, arow1 = m0 + 64 + srow;
    int brow0 = n0 + srow;      if (brow0 >= N) brow0 = N - 1;
    int brow1 = n0 + 64 + srow; if (brow1 >= N) brow1 = N - 1;
    char* dA = (char*)As + tid * 16;
    char* dB = (char*)Bs + tid * 16;

    f32x4 acc[4][4] = {};

    for (int k0 = 0; k0 < K; k0 += 32) {
        const __half* gA0 = A + (size_t)arow0 * lda + k0 + scol;
        const __half* gA1 = A + (size_t)arow1 * lda + k0 + scol;
        const __half* gB0 = B + (size_t)brow0 * ldb + k0 + scol;
        const __half* gB1 = B + (size_t)brow1 * ldb + k0 + scol;
        __syncthreads();                 // readers done with previous tile
        gload_lds16(gA0, dA);
        gload_lds16(gA1, dA + 4096);
        gload_lds16(gB0, dB);
        gload_lds16(gB1, dB + 4096);
        __syncthreads();                 // vmcnt(0) drain -> tile ready

        half8 af[4], bf[4];
#pragma unroll
        for (int f = 0; f < 4; f++) {
            af[f] = *(const half8*)&As[(wm * 64 + f * 16 + lr) * 32 + lk * 8];
            bf[f] = *(const half8*)&Bs[(wn * 64 + f * 16 + lr) * 32 + lk * 8];
        }
#pragma unroll
        for (int fm = 0; fm < 4; fm++)
#pragma unroll
            for (int fn = 0; fn < 4; fn++)
                acc[fm][fn] = __builtin_amdgcn_mfma_f32_16x16x32_f16(
                    af[fm], bf[fn], acc[fm][fn], 0, 0, 0);
    }

    // epilogue: C/D map row=(lane>>4)*4+j, col=lane&15  [m89-verified]
#pragma unroll
    for (int fm = 0; fm < 4; fm++) {
#pragma unroll
        for (int fn = 0; fn < 4; fn++) {
#pragma unroll
            for (int j = 0; j < 4; j++) {
                const int gm = m0 + wm * 64 + fm * 16 + lk * 4 + j;
                const int gn = n0 + wn * 64 + fn * 16 + lr;
                if (gn >= N) continue;
                float a = acc[fm][fn][j];
                if (epi == 1) {
                    a = tanhf(a);
                    ((__half*)Cv)[(size_t)gm * ldc + gn] = __float2half(a);
                } else if (epi == 2) {
                    a += bias[gn];
                    const float xv = X[(size_t)gm * 1024 + gn];
                    float xp = 0.f;
                    if (gm & (T - 1)) xp = X[(size_t)(gm - 1) * 1024 + gn];
                    ((__half*)Cv)[(size_t)gm * ldc + gn] =
                        __float2half(xv + (xp - xv) * a);
                } else if (epi == 3) {
                    a += bias[gn];
                    ((__half*)Cv)[(size_t)gm * ldc + gn] = __float2half(a);
                } else if (epi == 4) {
                    ((float*)Cv)[(size_t)gm * ldc + gn] = a;
                } else {
                    ((__half*)Cv)[(size_t)gm * ldc + gn] = __float2half(a);
                }
            }
        }
    }
}

// ---------------- prepass: pack E-line + ru ---------------------------------
// E layout per (bh,t): 192 uints (768B):
//   words [0..128)  : rk[k] = r(k) f16 | k(k) f16 << 16
//   words [128..192): dec f16 pairs (dec(2i) | dec(2i+1)<<16)
__global__ __launch_bounds__(256) void k_prep(
    const __half* __restrict__ R, const __half* __restrict__ Kk,
    const __half* __restrict__ W, const float* __restrict__ bonus,
    unsigned* __restrict__ Eu, float* __restrict__ RU, int T)
{
    const int tok = blockIdx.x;
    const int b = tok >> 11, t = tok & 2047;
    const int h = threadIdx.x >> 6, lane = threadIdx.x & 63;
    const size_t base = (size_t)tok * 512 + h * 128 + 2 * lane;
    const unsigned rr = *(const unsigned*)(R + base);   // r(2l), r(2l+1)
    const unsigned kk = *(const unsigned*)(Kk + base);
    const unsigned ww = *(const unsigned*)(W + base);
    const float2 rf = up2(rr), kf = up2(kk), wf = up2(ww);
    const float d0 = __expf(-__expf(wf.x));
    const float d1 = __expf(-__expf(wf.y));
    const float2 uf = *(const float2*)(bonus + h * 128 + 2 * lane);
    float ru = rf.x * uf.x * kf.x + rf.y * uf.y * kf.y;
#pragma unroll
    for (int off = 1; off < 64; off <<= 1) ru += __shfl_xor(ru, off);
    const int bh = b * 4 + h;
    unsigned* ep = Eu + (size_t)(bh * T + t) * 192;
    uint2 rkw;
    rkw.x = (rr & 0xFFFFu) | (kk << 16);           // r(2l)|k(2l)
    rkw.y = (rr >> 16) | (kk & 0xFFFF0000u);       // r(2l+1)|k(2l+1)
    *(uint2*)(ep + 2 * lane) = rkw;
    ep[128 + lane] = (unsigned)f2h(d0) | ((unsigned)f2h(d1) << 16);
    if (lane == 0) RU[(size_t)bh * T + t] = ru;
}

// ---------------- cooperative chunked scan (paired steps) -------------------
// Block = (bh, c, vq): 256 thr. Thread: kg = tid&15 (8 k-slots), vg = tid>>4
// (4 v-cols). S[32] = S[kk*4+vi]. Waves 0,1 stage steps 2p,2p+1 of each pair
// into a 4-slot LDS ring; raw s_barrier + lgkmcnt(0) per pair. rk uint4s
// stored XOR-swizzled (i^(i>>3)). Chunk states in f16 (Cbuf).
template<bool PART>
__global__ __launch_bounds__(256) void rwkv_coop(
    const uint4* __restrict__ E, const __half* __restrict__ V,
    const float* __restrict__ RU, const __half* __restrict__ Cin,
    __half* __restrict__ Cout, float* __restrict__ Abuf,
    __half* __restrict__ O, int T)
{
    __shared__ uint4 sE[4][96];
    __shared__ uint4 sV[4][16];
    __shared__ float sRU[4][2];

    const int p = blockIdx.x;
    int bh, c, vq;
    if (PART) {
        const int l = (p & 7) * 112 + (p >> 3);       // 896 blocks, bijective
        bh = l / 28; const int rem = l - bh * 28; c = rem >> 2; vq = rem & 3;
    } else {
        const int l = (p & 7) * 128 + (p >> 3);       // 1024 blocks, bijective
        bh = l >> 5; c = (l >> 2) & 7; vq = l & 3;
    }
    const int b = bh >> 2, h = bh & 3;
    const int tid = threadIdx.x;
    const int w = tid >> 6, lane = tid & 63;
    const int kg = tid & 15, vg = tid >> 4;
    const int t0 = c * CL;

    const uint4* Eg = E + (size_t)(bh * T + t0) * 48;
    const uint4* Vgp = (const uint4*)(V + ((size_t)b * T + t0) * 1024 + h * 256 + vq * 64);
    const float* RUp = RU + (size_t)bh * T + t0;
    __half* Op = O + ((size_t)b * T + t0) * 1024 + h * 256 + vq * 64 + vg * 4;

    float S[32];
    float Aacc[8];
    if (!PART && c) {
        const __half* Sp = Cin + ((size_t)(c - 1) * 32 + bh) * 32768 + vq * 64 + vg * 4;
#pragma unroll
        for (int kk = 0; kk < 8; kk++) {
            const ushort4 s4 = *(const ushort4*)(Sp + (size_t)(kg * 8 + kk) * 256);
            S[kk * 4 + 0] = hbits2f(s4.x); S[kk * 4 + 1] = hbits2f(s4.y);
            S[kk * 4 + 2] = hbits2f(s4.z); S[kk * 4 + 3] = hbits2f(s4.w);
        }
    } else {
#pragma unroll
        for (int j = 0; j < 32; j++) S[j] = 0.f;
    }
#pragma unroll
    for (int j = 0; j < 8; j++) Aacc[j] = 1.f;

    // swizzled rk indices for this kg
    const int i0 = (kg * 2) ^ ((kg * 2) >> 3);
    const int i1 = (kg * 2 + 1) ^ ((kg * 2 + 1) >> 3);

#define ISSUE(BE, BV, BR, PP)                                                 \
    if (w < 2 && (PP) < NP) {                                                 \
        const int tt = (PP) * 2 + w;                                          \
        if (lane < 48)      BE = Eg[(size_t)tt * 48 + lane];                  \
        else if (lane < 56) BV = Vgp[(size_t)tt * 128 + (lane - 48)];         \
        if (lane == 56)     BR = RUp[tt];                                     \
    }

#define STAGE(BE, BV, BR, SLOT)                                               \
    if (w < 2) {                                                              \
        if (lane < 32)      sE[SLOT][w * 48 + (lane ^ (lane >> 3))] = BE;     \
        else if (lane < 48) sE[SLOT][w * 48 + lane] = BE;                     \
        else if (lane < 56) sV[SLOT][w * 8 + (lane - 48)] = BV;               \
        if (lane == 56)     sRU[SLOT][w] = BR;                                \
    }

#define BAR() do {                                                            \
        asm volatile("s_waitcnt lgkmcnt(0)" ::: "memory");                    \
        __builtin_amdgcn_s_barrier();                                         \
        __builtin_amdgcn_sched_barrier(0);                                    \
    } while (0)

#define COMPUTE(SLOT, SUB, TT)                                                \
    {                                                                         \
        const uint4 rka = sE[SLOT][(SUB) * 48 + i0];                          \
        const uint4 rkb = sE[SLOT][(SUB) * 48 + i1];                          \
        const uint4 dq  = sE[SLOT][(SUB) * 48 + 32 + kg];                     \
        const uint2 vw  = *(const uint2*)((const unsigned*)&sV[SLOT][(SUB) * 8] + vg * 2); \
        const unsigned rw_[8] = {rka.x, rka.y, rka.z, rka.w,                  \
                                 rkb.x, rkb.y, rkb.z, rkb.w};                 \
        const unsigned dw_[4] = {dq.x, dq.y, dq.z, dq.w};                     \
        float r_[8], k_[8], d_[8], vv_[4];                                    \
        _Pragma("unroll") for (int j = 0; j < 8; j++) {                       \
            const float2 rk = up2(rw_[j]); r_[j] = rk.x; k_[j] = rk.y;        \
        }                                                                     \
        _Pragma("unroll") for (int j = 0; j < 4; j++) {                       \
            const float2 dd = up2(dw_[j]); d_[2 * j] = dd.x; d_[2 * j + 1] = dd.y; \
        }                                                                     \
        { const float2 va = up2(vw.x), vb = up2(vw.y);                        \
          vv_[0] = va.x; vv_[1] = va.y; vv_[2] = vb.x; vv_[3] = vb.y; }       \
        float osum[4] = {0.f, 0.f, 0.f, 0.f};                                 \
        _Pragma("unroll") for (int kk = 0; kk < 8; kk++) {                    \
            _Pragma("unroll") for (int vi = 0; vi < 4; vi++) {                \
                osum[vi] = fmaf(r_[kk], S[kk * 4 + vi], osum[vi]);            \
                S[kk * 4 + vi] = fmaf(d_[kk], S[kk * 4 + vi], k_[kk] * vv_[vi]); \
            }                                                                 \
            if (PART) Aacc[kk] *= d_[kk];                                     \
        }                                                                     \
        if (!PART) {                                                          \
            _Pragma("unroll") for (int vi = 0; vi < 4; vi++) {                \
                osum[vi] += __shfl_xor(osum[vi], 1);                          \
                osum[vi] += __shfl_xor(osum[vi], 2);                          \
                osum[vi] += __shfl_xor(osum[vi], 4);                          \
                osum[vi] += __shfl_xor(osum[vi], 8);                          \
            }                                                                 \
            if (kg == 0) {                                                    \
                const float ru_ = sRU[SLOT][SUB];                             \
                ushort4 ou;                                                   \
                ou.x = f2h(osum[0] + ru_ * vv_[0]);                           \
                ou.y = f2h(osum[1] + ru_ * vv_[1]);                           \
                ou.z = f2h(osum[2] + ru_ * vv_[2]);                           \
                ou.w = f2h(osum[3] + ru_ * vv_[3]);                           \
                *(ushort4*)(Op + (size_t)(TT) * 1024) = ou;                   \
            }                                                                 \
        }                                                                     \
    }

#define COMPUTE2(SLOT, PP)  COMPUTE(SLOT, 0, (PP) * 2) COMPUTE(SLOT, 1, (PP) * 2 + 1)

    uint4 e0 = {}, e1 = {}, e2 = {}, e3 = {};
    uint4 v0 = {}, v1 = {}, v2 = {}, v3 = {};
    float r0 = 0.f, r1 = 0.f, r2 = 0.f, r3 = 0.f;

    ISSUE(e0, v0, r0, 0)
    ISSUE(e1, v1, r1, 1)
    ISSUE(e2, v2, r2, 2)
    ISSUE(e3, v3, r3, 3)
    STAGE(e0, v0, r0, 0)
    BAR();

    for (int ps = 0; ps < NP; ps += 4) {
        STAGE(e1, v1, r1, 1)
        ISSUE(e0, v0, r0, ps + 4)
        COMPUTE2(0, ps)
        BAR();
        STAGE(e2, v2, r2, 2)
        ISSUE(e1, v1, r1, ps + 5)
        COMPUTE2(1, ps + 1)
        BAR();
        STAGE(e3, v3, r3, 3)
        ISSUE(e2, v2, r2, ps + 6)
        COMPUTE2(2, ps + 2)
        BAR();
        if (ps + 4 < NP) STAGE(e0, v0, r0, 0)
        ISSUE(e3, v3, r3, ps + 7)
        COMPUTE2(3, ps + 3)
        BAR();
    }

    if (PART) {
        __half* Cw = Cout + ((size_t)c * 32 + bh) * 32768 + vq * 64 + vg * 4;
#pragma unroll
        for (int kk = 0; kk < 8; kk++) {
            ushort4 s4;
            s4.x = f2h(S[kk * 4 + 0]); s4.y = f2h(S[kk * 4 + 1]);
            s4.z = f2h(S[kk * 4 + 2]); s4.w = f2h(S[kk * 4 + 3]);
            *(ushort4*)(Cw + (size_t)(kg * 8 + kk) * 256) = s4;
        }
        if (vg == 0) {
            float* Aw = Abuf + ((size_t)c * 32 + bh) * 128 + kg * 8;
#pragma unroll
            for (int kk = 0; kk < 8; kk++) Aw[kk] = Aacc[kk];
        }
    }
#undef ISSUE
#undef STAGE
#undef BAR
#undef COMPUTE
#undef COMPUTE2
}

// ---------------- combine: C[c-1] := S_start(c), c = 1..7 -------------------
__global__ __launch_bounds__(256) void rwkv_comb(
    __half* __restrict__ C, const float* __restrict__ A)
{
    const int gid = blockIdx.x * 256 + threadIdx.x;   // 1M threads
    const int bh = gid >> 15;
    const int elem = gid & 32767;
    const int k = elem >> 8;
    float s = hbits2f(*(const unsigned short*)(C + (size_t)bh * 32768 + elem));
#pragma unroll
    for (int c = 1; c < NC - 1; ++c) {
        const float a = A[(size_t)(c * 32 + bh) * 128 + k];
        __half* cp = C + ((size_t)c * 32 + bh) * 32768 + elem;
        s = a * s + hbits2f(*(const unsigned short*)cp);
        *(unsigned short*)cp = f2h(s);
    }
}

// ---------------- groupnorm + silu gate (f16 in/out) ------------------------
__global__ __launch_bounds__(256) void gn_gate(
    const __half* __restrict__ Obuf, const __half* __restrict__ G,
    const float* __restrict__ gnw, const float* __restrict__ gnb,
    __half* __restrict__ Y)
{
    const int token = blockIdx.x;
    const int wave = threadIdx.x >> 6, lane = threadIdx.x & 63;
    const size_t base = (size_t)token * 1024 + wave * 256 + lane * 4;
    const ushort4 xu = *(const ushort4*)(Obuf + base);
    const float x0 = hbits2f(xu.x), x1 = hbits2f(xu.y),
                x2 = hbits2f(xu.z), x3 = hbits2f(xu.w);
    float sum = x0 + x1 + x2 + x3;
    float ssq = x0 * x0 + x1 * x1 + x2 * x2 + x3 * x3;
#pragma unroll
    for (int off = 32; off >= 1; off >>= 1) {
        sum += __shfl_xor(sum, off);
        ssq += __shfl_xor(ssq, off);
    }
    const float mean = sum * (1.f / 256.f);
    const float var = ssq * (1.f / 256.f) - mean * mean;
    const float rstd = rsqrtf(var + 1e-5f);
    const int c0 = wave * 256 + lane * 4;
    const float4 w4 = *(const float4*)(gnw + c0);
    const float4 b4 = *(const float4*)(gnb + c0);
    const ushort4 gu = *(const ushort4*)(G + base);
    const float g0 = hbits2f(gu.x), g1 = hbits2f(gu.y),
                g2 = hbits2f(gu.z), g3 = hbits2f(gu.w);
    ushort4 y;
    y.x = f2h(((x0 - mean) * rstd * w4.x + b4.x) * (g0 / (1.f + __expf(-g0))));
    y.y = f2h(((x1 - mean) * rstd * w4.y + b4.y) * (g1 / (1.f + __expf(-g1))));
    y.z = f2h(((x2 - mean) * rstd * w4.z + b4.z) * (g2 / (1.f + __expf(-g2))));
    y.w = f2h(((x3 - mean) * rstd * w4.w + b4.w) * (g3 / (1.f + __expf(-g3))));
    *(ushort4*)(Y + base) = y;
}

// ---------------------------------------------------------------------------
extern "C" void kernel_launch(void* const* d_in, const int* in_sizes, int n_in,
                              void* d_out, int out_size, void* d_ws, size_t ws_size,
                              hipStream_t stream)
{
    (void)in_sizes; (void)n_in; (void)out_size; (void)ws_size;
    const float* x      = (const float*)d_in[0];
    const float* mu_x   = (const float*)d_in[1];
    const float* W_x1   = (const float*)d_in[2];
    const float* W_x2   = (const float*)d_in[3];
    const float* x_bias = (const float*)d_in[4];
    const float* W_r    = (const float*)d_in[5];
    const float* W_k    = (const float*)d_in[6];
    const float* W_v    = (const float*)d_in[7];
    const float* W_g    = (const float*)d_in[8];
    const float* A_w    = (const float*)d_in[9];
    const float* B_w    = (const float*)d_in[10];
    const float* b_w    = (const float*)d_in[11];
    const float* bonus  = (const float*)d_in[12];
    const float* gnw    = (const float*)d_in[13];
    const float* gnb    = (const float*)d_in[14];
    const float* W_o    = (const float*)d_in[15];

    const int B = 8, T = 2048, M = B * T;

    // d_out: [xw_h | inb_h] f16 -> E (48MiB packed scan lines) -> final f32
    __half* xwh  = (__half*)d_out;
    __half* inbh = xwh + (size_t)M * 1024;

    // ws layout (identical to round-8/9/10, proven to fit)
    __half* z   = (__half*)d_ws;                    // M*160
    __half* w1  = z   + (size_t)M * 160;            // M*64
    __half* rs  = w1  + (size_t)M * 64;             // M*512
    __half* ks  = rs  + (size_t)M * 512;            // M*512
    __half* wsm = ks  + (size_t)M * 512;            // M*512 (w stream)
    __half* vs  = wsm + (size_t)M * 512;            // M*1024
    __half* gs  = vs  + (size_t)M * 1024;           // M*1024
    float*  ru  = (float*)(gs + (size_t)M * 1024);  // 32*T f32
    __half* wgt = (__half*)(ru + (size_t)32 * T);   // f16 weights
    __half* oh  = rs;                               // overlay: o f16 (r+k dead)
    __half* yb  = wsm;                              // overlay: y f16 (post-scan)
    __half* Cbuf = wsm;                             // overlay: 7*32*32768 f16 = 14.7MB
    float*  Abuf = (float*)z;                       // overlay: 7*32*128 f32

    __half* W_x1h = wgt;                 // 160*1024
    __half* W_x2h = W_x1h + 163840;      // 1024*160
    __half* W_rh  = W_x2h + 163840;      // 512*1024
    __half* W_kh  = W_rh + 524288;
    __half* W_vh  = W_kh + 524288;       // 1024*1024
    __half* W_gh  = W_vh + 1048576;
    __half* A_wh  = W_gh + 1048576;      // 64*1024
    __half* B_wh  = A_wh + 65536;        // 512*64
    __half* W_oh  = B_wh + 32768;        // 1024*1024

    const dim3 blk(256);
    auto cgrid = [](int n) { return dim3((n / 4 + 255) / 256); };
    cast16<<<cgrid(163840), blk, 0, stream>>>(W_x1, W_x1h, 163840 / 4);
    cast16<<<cgrid(163840), blk, 0, stream>>>(W_x2, W_x2h, 163840 / 4);
    cast16<<<cgrid(524288), blk, 0, stream>>>(W_r, W_rh, 524288 / 4);
    cast16<<<cgrid(524288), blk, 0, stream>>>(W_k, W_kh, 524288 / 4);
    cast16<<<cgrid(1048576), blk, 0, stream>>>(W_v, W_vh, 1048576 / 4);
    cast16<<<cgrid(1048576), blk, 0, stream>>>(W_g, W_gh, 1048576 / 4);
    cast16<<<cgrid(65536), blk, 0, stream>>>(A_w, A_wh, 65536 / 4);
    cast16<<<cgrid(32768), blk, 0, stream>>>(B_w, B_wh, 32768 / 4);
    cast16<<<cgrid(1048576), blk, 0, stream>>>(W_o, W_oh, 1048576 / 4);

    // 1. xw = lerp(x, mu_x) -> f16
    k_xw_h<<<(M * 256 + 255) / 256, blk, 0, stream>>>(x, mu_x, xwh, M, T);

    auto ggrid = [&](int N) { return dim3((N + 127) / 128, M / 128); };

    // 2. z = tanh(xw @ W_x1^T)
    gemm16<<<ggrid(160), blk, 0, stream>>>(xwh, 1024, W_x1h, 1024, z, 160,
                                           M, 160, 1024, nullptr, 1, nullptr, T);

    // 3. branches
    for (int n = 0; n < 5; ++n) {
        gemm16<<<ggrid(1024), blk, 0, stream>>>(z + n * 32, 160, W_x2h + n * 32, 160,
                                                inbh, 1024, M, 1024, 32,
                                                x_bias + n * 1024, 2, x, T);
        if (n == 1) {
            gemm16<<<ggrid(64), blk, 0, stream>>>(inbh, 1024, A_wh, 1024, w1, 64,
                                                  M, 64, 1024, nullptr, 1, nullptr, T);
            gemm16<<<ggrid(512), blk, 0, stream>>>(w1, 64, B_wh, 64, wsm, 512,
                                                   M, 512, 64, b_w, 3, nullptr, T);
        } else {
            __half* Cp = (n == 0) ? rs : (n == 2) ? ks : (n == 3) ? vs : gs;
            const __half* Wp = (n == 0) ? W_rh : (n == 2) ? W_kh : (n == 3) ? W_vh : W_gh;
            const int N = (n == 0 || n == 2) ? 512 : 1024;
            gemm16<<<ggrid(N), blk, 0, stream>>>(inbh, 1024, Wp, 1024, Cp, N,
                                                 M, N, 1024, nullptr, 0, nullptr, T);
        }
    }

    // 4. prepass -> packed E lines (d_out; xwh/inbh dead), ru
    k_prep<<<dim3(M), blk, 0, stream>>>(rs, ks, wsm, bonus,
                                        (unsigned*)d_out, ru, T);

    // 5a. chunk summaries (c=0..6) -> Cbuf (f16), Abuf
    rwkv_coop<true><<<dim3(896), blk, 0, stream>>>(
        (const uint4*)d_out, vs, ru, Cbuf, Cbuf, Abuf, oh, T);
    // 5b. combine
    rwkv_comb<<<dim3(4096), blk, 0, stream>>>(Cbuf, Abuf);
    // 5c. chunk-local scan with outputs -> o f16
    rwkv_coop<false><<<dim3(1024), blk, 0, stream>>>(
        (const uint4*)d_out, vs, ru, Cbuf, Cbuf, Abuf, oh, T);

    // 6. groupnorm + gate -> yb
    gn_gate<<<dim3(M), blk, 0, stream>>>(oh, gs, gnw, gnb, yb);

    // 7. out = y @ W_o^T -> d_out f32 (E dead)
    gemm16<<<ggrid(1024), blk, 0, stream>>>(yb, 1024, W_oh, 1024, d_out, 1024,
                                            M, 1024, 1024, nullptr, 4, nullptr, T);
}